// Round 2
// baseline (9501.018 us; speedup 1.0000x reference)
//
#include <hip/hip_runtime.h>
#include <stdint.h>

#define JAX_PARTITIONABLE 1

static constexpr int C_ = 256;
static constexpr int T_ = 1024;
static constexpr int N_ = 32768;   // 32 * 1024
static constexpr int K_ = 1024;

// ---------------- Threefry2x32, 20 rounds (JAX-compatible) ----------------
__host__ __device__ __forceinline__ void tf2x32(uint32_t k0, uint32_t k1,
                                                uint32_t x0, uint32_t x1,
                                                uint32_t& o0, uint32_t& o1) {
  const uint32_t ks2 = k0 ^ k1 ^ 0x1BD11BDAu;
  uint32_t v0 = x0 + k0, v1 = x1 + k1;
#define TFR(d) { v0 += v1; v1 = (v1 << d) | (v1 >> (32 - d)); v1 ^= v0; }
#define TF4A TFR(13) TFR(15) TFR(26) TFR(6)
#define TF4B TFR(17) TFR(29) TFR(16) TFR(24)
  TF4A v0 += k1;  v1 += ks2 + 1u;
  TF4B v0 += ks2; v1 += k0 + 2u;
  TF4A v0 += k0;  v1 += k1 + 3u;
  TF4B v0 += k1;  v1 += ks2 + 4u;
  TF4A v0 += ks2; v1 += k0 + 5u;
  o0 = v0; o1 = v1;
#undef TFR
#undef TF4A
#undef TF4B
}

// ---------------- PRNG / permutation kernels (verified correct in R1) ----------------
__global__ void bits_kernel(uint32_t k0, uint32_t k1, unsigned long long* __restrict__ keys) {
#if JAX_PARTITIONABLE
  const int i = blockIdx.x * 256 + threadIdx.x;          // 32768 threads
  uint32_t o0, o1; tf2x32(k0, k1, 0u, (uint32_t)i, o0, o1);
  keys[i] = (((unsigned long long)(o0 ^ o1)) << 32) | (unsigned)i;
#else
  const int j = blockIdx.x * 256 + threadIdx.x;          // 16384 threads
  uint32_t o0, o1; tf2x32(k0, k1, (uint32_t)j, (uint32_t)(j + 16384), o0, o1);
  keys[j]         = (((unsigned long long)o0) << 32) | (unsigned)j;
  keys[j + 16384] = (((unsigned long long)o1) << 32) | (unsigned)(j + 16384);
#endif
}

// rank[p] = #{ j : key[j] < key[p] }  (keys all distinct -> exact stable-sort position)
__global__ void rank_kernel(const unsigned long long* __restrict__ keys, int* __restrict__ rank) {
  const int p = blockIdx.x * 256 + threadIdx.x;
  const unsigned long long my = keys[p];
  const int base = blockIdx.y * 4096;
  int cnt = 0;
  #pragma unroll 8
  for (int j = 0; j < 4096; ++j) cnt += (keys[base + j] < my) ? 1 : 0;
  atomicAdd(&rank[p], cnt);
}

__global__ void scatter1_kernel(const int* __restrict__ rank, int* __restrict__ val) {
  const int p = blockIdx.x * 256 + threadIdx.x;
  val[rank[p]] = p;
}

__global__ void scatter2_kernel(const int* __restrict__ rank, const int* __restrict__ val,
                                int* __restrict__ perm) {
  const int q = blockIdx.x * 256 + threadIdx.x;
  const int r = rank[q];
  if (r < K_) perm[r] = val[q];
}

// ---------------- f64 block reduce (256 threads) ----------------
__device__ __forceinline__ double block_reduce_256_f64(double v, double* red) {
  #pragma unroll
  for (int s = 1; s < 64; s <<= 1) v += __shfl_xor(v, s, 64);
  if ((threadIdx.x & 63) == 0) red[threadIdx.x >> 6] = v;
  __syncthreads();
  return red[0] + red[1] + red[2] + red[3];
}

__global__ void init_ema_kernel(const float* __restrict__ x, const int* __restrict__ perm,
                                float* __restrict__ ema, double* __restrict__ csq) {
  __shared__ double red[4];
  const int k = blockIdx.x, c = threadIdx.x;
  const int n = perm[k];
  const int b = n >> 10, t = n & 1023;
  const float v = x[(size_t)b * (C_ * T_) + (size_t)c * T_ + t];
  ema[(size_t)k * C_ + c] = v;
  const double s = block_reduce_256_f64((double)v * (double)v, red);
  if (c == 0) csq[k] = s;
}

// EMA update replicating the reference's f32 arithmetic exactly (no fma contraction);
// sums arrive as f64 (exact-math), rounded once to f32 like the ref's f32 segment_sum.
__global__ void update_kernel(float* __restrict__ ema, const double* __restrict__ sums,
                              const int* __restrict__ counts, double* __restrict__ csq) {
  __shared__ double red[4];
  const int k = blockIdx.x, c = threadIdx.x;
  const size_t idx = ((size_t)k << 8) + c;
  const int cnt = counts[k];
  const float e = ema[idx];
  float center;
  if (cnt == 0) {
    center = e;                                   // jnp.where(counts==0, ema, ...)
  } else {
    const float s32 = (float)sums[idx];
    const float denom = __fadd_rn((float)cnt, 1e-5f);
    center = __fdiv_rn(s32, denom);               // centers = sums / (counts + EPS), f32 IEEE
  }
  const float ne = __fadd_rn(__fmul_rn(e, 0.99f), __fmul_rn(0.01f, center));
  ema[idx] = ne;
  const double s = block_reduce_256_f64((double)ne * (double)ne, red);
  if (c == 0) csq[k] = s;
}

// ---------------- fused distance+argmin (+ f64 segment-sum scatter) ----------------
// Block: 64 points x all 1024 clusters. 256 threads = 16 ty (4 pts) x 16 tx (8 k's per k-tile).
// argmin on (csq[k] - 2*dot) in f64: x^2 is constant per point and cancels.
template<int WRITE>
__global__ __launch_bounds__(256, 2) void assign_kernel(
    const float* __restrict__ x, const float* __restrict__ ema,
    const double* __restrict__ csq,
    double* __restrict__ sums, int* __restrict__ counts, int* __restrict__ out) {
  __shared__ float  A[C_][64];    // 64 KiB: whole 64-point tile, [c][point]
  __shared__ double Bl[8][128];   // 8 KiB: current 8-channel chunk of 128 centers, as f64
  __shared__ int lab[64];

  const int tid = threadIdx.x;
  const int n0 = blockIdx.x * 64;
  const int b = n0 >> 10, t0 = n0 & 1023;
  const float* xb = x + (size_t)b * (C_ * T_);

  #pragma unroll
  for (int i = 0; i < 16; ++i) {
    const int idx = tid + i * 256;               // 4096 float4s
    const int cl = idx >> 4, tl = idx & 15;
    *(float4*)&A[cl][tl << 2] = *(const float4*)(xb + (size_t)cl * T_ + t0 + (tl << 2));
  }

  const int ty = tid >> 4;     // 4 points each
  const int tx = tid & 15;

  double bestd[4]; int bestk[4];
  #pragma unroll
  for (int i = 0; i < 4; ++i) { bestd[i] = 1e300; bestk[i] = 0; }

  for (int kt = 0; kt < 8; ++kt) {
    const int k0 = kt << 7;
    double acc[4][8];
    #pragma unroll
    for (int i = 0; i < 4; ++i)
      #pragma unroll
      for (int j = 0; j < 8; ++j) acc[i][j] = 0.0;

    for (int cc = 0; cc < 32; ++cc) {
      const int c0 = cc << 3;
      __syncthreads();
      { // stage B chunk as f64: 128 k-rows x 8 channels
        const int kl = tid >> 1, h = tid & 1;
        const float4 v = *(const float4*)(ema + (((size_t)(k0 + kl)) << 8) + c0 + (h << 2));
        Bl[(h << 2) + 0][kl] = (double)v.x;
        Bl[(h << 2) + 1][kl] = (double)v.y;
        Bl[(h << 2) + 2][kl] = (double)v.z;
        Bl[(h << 2) + 3][kl] = (double)v.w;
      }
      __syncthreads();
      #pragma unroll
      for (int c = 0; c < 8; ++c) {
        const float4 av = *(const float4*)&A[c0 + c][ty << 2];
        const double aa[4] = {(double)av.x, (double)av.y, (double)av.z, (double)av.w};
        double bb[8];
        #pragma unroll
        for (int jj = 0; jj < 4; ++jj) {
          const double2 bv = *(const double2*)&Bl[c][(tx << 1) + (jj << 5)];
          bb[2 * jj] = bv.x; bb[2 * jj + 1] = bv.y;
        }
        #pragma unroll
        for (int i = 0; i < 4; ++i)
          #pragma unroll
          for (int j = 0; j < 8; ++j)
            acc[i][j] = fma(aa[i], bb[j], acc[i][j]);
      }
    }
    // epilogue for this k-tile: ascending k within thread -> '<' keeps lowest-k tie
    #pragma unroll
    for (int j = 0; j < 8; ++j) {
      const int kl = ((j >> 1) << 5) + (tx << 1) + (j & 1);
      const int kk = k0 + kl;
      const double cq = csq[kk];
      #pragma unroll
      for (int i = 0; i < 4; ++i) {
        const double d = cq - 2.0 * acc[i][j];
        if (d < bestd[i] || (d == bestd[i] && kk < bestk[i])) { bestd[i] = d; bestk[i] = kk; }
      }
    }
  }

  // argmin across the 16 tx lanes (lane bits 0..3); lexicographic (d, k)
  #pragma unroll
  for (int i = 0; i < 4; ++i) {
    #pragma unroll
    for (int s = 1; s < 16; s <<= 1) {
      const double od = __shfl_xor(bestd[i], s, 64);
      const int    ok = __shfl_xor(bestk[i], s, 64);
      if (od < bestd[i] || (od == bestd[i] && ok < bestk[i])) { bestd[i] = od; bestk[i] = ok; }
    }
    if (tx == 0) {
      if (WRITE) out[n0 + (ty << 2) + i] = bestk[i];
      else lab[(ty << 2) + i] = bestk[i];
    }
  }

  if (!WRITE) {
    __syncthreads();
    if (tid < 64) atomicAdd(&counts[lab[tid]], 1);
    const int cl = tid >> 5, tl = tid & 31;      // 8 channel-groups x 32 point-lanes
    #pragma unroll 1
    for (int cc = 0; cc < 32; ++cc) {
      const int c = (cc << 3) + cl;
      #pragma unroll
      for (int e = 0; e < 2; ++e) {
        const int p = (tl << 1) + e;
        unsafeAtomicAdd(&sums[(((size_t)lab[p]) << 8) + c], (double)A[c][p]);
      }
    }
  }
}

// ---------------- launch ----------------
extern "C" void kernel_launch(void* const* d_in, const int* in_sizes, int n_in,
                              void* d_out, int out_size, void* d_ws, size_t ws_size,
                              hipStream_t stream) {
  const float* x = (const float*)d_in[0];
  int* out = (int*)d_out;
  char* ws = (char*)d_ws;

  unsigned long long* keys = (unsigned long long*)(ws + 0);        // 256 KiB
  int*    rank  = (int*)   (ws + 262144);                          // 128 KiB
  int*    val1  = (int*)   (ws + 393216);                          // 128 KiB
  int*    perm  = (int*)   (ws + 524288);                          // 4 KiB
  float*  ema   = (float*) (ws + 528384);                          // 1 MiB
  double* csq   = (double*)(ws + 1576960);                         // 8 KiB
  double* sums  = (double*)(ws + 1585152);                         // 2 MiB
  int*    counts= (int*)   (ws + 3682304);                         // 4 KiB (right after sums)

  // host-side threefry: the two per-round sort subkeys from key(1) = (0,1)
  uint32_t s1h, s1l, s2h, s2l;
  {
#if JAX_PARTITIONABLE
    uint32_t ch, cl;
    tf2x32(0u, 1u, 0u, 0u, ch, cl);      // carried key = threefry(key,(0,0))
    tf2x32(0u, 1u, 0u, 1u, s1h, s1l);    // subkey 1    = threefry(key,(0,1))
    tf2x32(ch, cl, 0u, 1u, s2h, s2l);    // subkey 2    = threefry(carried,(0,1))
#else
    uint32_t a0, a1, b0, b1, ch, cl;
    tf2x32(0u, 1u, 0u, 2u, a0, a1); tf2x32(0u, 1u, 1u, 3u, b0, b1);
    ch = a0; cl = b0; s1h = a1; s1l = b1;
    tf2x32(ch, cl, 0u, 2u, a0, a1); tf2x32(ch, cl, 1u, 3u, b0, b1);
    s2h = a1; s2l = b1;
#endif
  }

  // stable sort round 1: rank composite (bits<<32|i), scatter arange
#if JAX_PARTITIONABLE
  bits_kernel<<<128, 256, 0, stream>>>(s1h, s1l, keys);
#else
  bits_kernel<<<64, 256, 0, stream>>>(s1h, s1l, keys);
#endif
  hipMemsetAsync(rank, 0, N_ * 4, stream);
  rank_kernel<<<dim3(128, 8), 256, 0, stream>>>(keys, rank);
  scatter1_kernel<<<128, 256, 0, stream>>>(rank, val1);

  // stable sort round 2; keep only first K positions -> perm
#if JAX_PARTITIONABLE
  bits_kernel<<<128, 256, 0, stream>>>(s2h, s2l, keys);
#else
  bits_kernel<<<64, 256, 0, stream>>>(s2h, s2l, keys);
#endif
  hipMemsetAsync(rank, 0, N_ * 4, stream);
  rank_kernel<<<dim3(128, 8), 256, 0, stream>>>(keys, rank);
  scatter2_kernel<<<128, 256, 0, stream>>>(rank, val1, perm);

  init_ema_kernel<<<K_, 256, 0, stream>>>(x, perm, ema, csq);

  for (int it = 0; it < 10; ++it) {
    hipMemsetAsync(sums, 0, (size_t)K_ * C_ * 8 + K_ * 4, stream);  // sums(f64) + counts
    assign_kernel<0><<<512, 256, 0, stream>>>(x, ema, csq, sums, counts, nullptr);
    update_kernel<<<K_, 256, 0, stream>>>(ema, sums, counts, csq);
  }
  assign_kernel<1><<<512, 256, 0, stream>>>(x, ema, csq, nullptr, nullptr, out);
}

// Round 3
// 8234.475 us; speedup vs baseline: 1.1538x; 1.1538x over previous
//
#include <hip/hip_runtime.h>
#include <stdint.h>

#define JAX_PARTITIONABLE 1

static constexpr int C_ = 256;
static constexpr int T_ = 1024;
static constexpr int N_ = 32768;   // 32 * 1024
static constexpr int K_ = 1024;
static constexpr float MARGIN_ = 0.02f;   // >> 5x the f32 dot-chain error bound (~4e-3)

// ---------------- Threefry2x32, 20 rounds (JAX-compatible) ----------------
__host__ __device__ __forceinline__ void tf2x32(uint32_t k0, uint32_t k1,
                                                uint32_t x0, uint32_t x1,
                                                uint32_t& o0, uint32_t& o1) {
  const uint32_t ks2 = k0 ^ k1 ^ 0x1BD11BDAu;
  uint32_t v0 = x0 + k0, v1 = x1 + k1;
#define TFR(d) { v0 += v1; v1 = (v1 << d) | (v1 >> (32 - d)); v1 ^= v0; }
#define TF4A TFR(13) TFR(15) TFR(26) TFR(6)
#define TF4B TFR(17) TFR(29) TFR(16) TFR(24)
  TF4A v0 += k1;  v1 += ks2 + 1u;
  TF4B v0 += ks2; v1 += k0 + 2u;
  TF4A v0 += k0;  v1 += k1 + 3u;
  TF4B v0 += k1;  v1 += ks2 + 4u;
  TF4A v0 += ks2; v1 += k0 + 5u;
  o0 = v0; o1 = v1;
#undef TFR
#undef TF4A
#undef TF4B
}

// ---------------- PRNG / permutation kernels (validated in R2) ----------------
__global__ void bits_kernel(uint32_t k0, uint32_t k1, unsigned long long* __restrict__ keys) {
#if JAX_PARTITIONABLE
  const int i = blockIdx.x * 256 + threadIdx.x;
  uint32_t o0, o1; tf2x32(k0, k1, 0u, (uint32_t)i, o0, o1);
  keys[i] = (((unsigned long long)(o0 ^ o1)) << 32) | (unsigned)i;
#else
  const int j = blockIdx.x * 256 + threadIdx.x;
  uint32_t o0, o1; tf2x32(k0, k1, (uint32_t)j, (uint32_t)(j + 16384), o0, o1);
  keys[j]         = (((unsigned long long)o0) << 32) | (unsigned)j;
  keys[j + 16384] = (((unsigned long long)o1) << 32) | (unsigned)(j + 16384);
#endif
}

__global__ void rank_kernel(const unsigned long long* __restrict__ keys, int* __restrict__ rank) {
  const int p = blockIdx.x * 256 + threadIdx.x;
  const unsigned long long my = keys[p];
  const int base = blockIdx.y * 4096;
  int cnt = 0;
  #pragma unroll 8
  for (int j = 0; j < 4096; ++j) cnt += (keys[base + j] < my) ? 1 : 0;
  atomicAdd(&rank[p], cnt);
}

__global__ void scatter1_kernel(const int* __restrict__ rank, int* __restrict__ val) {
  const int p = blockIdx.x * 256 + threadIdx.x;
  val[rank[p]] = p;
}

__global__ void scatter2_kernel(const int* __restrict__ rank, const int* __restrict__ val,
                                int* __restrict__ perm) {
  const int q = blockIdx.x * 256 + threadIdx.x;
  const int r = rank[q];
  if (r < K_) perm[r] = val[q];
}

// ---------------- f64 block reduce (256 threads) ----------------
__device__ __forceinline__ double block_reduce_256_f64(double v, double* red) {
  #pragma unroll
  for (int s = 1; s < 64; s <<= 1) v += __shfl_xor(v, s, 64);
  if ((threadIdx.x & 63) == 0) red[threadIdx.x >> 6] = v;
  __syncthreads();
  return red[0] + red[1] + red[2] + red[3];
}

__global__ void init_ema_kernel(const float* __restrict__ x, const int* __restrict__ perm,
                                float* __restrict__ ema, float* __restrict__ emaT,
                                double* __restrict__ csq, float* __restrict__ csq32) {
  __shared__ double red[4];
  const int k = blockIdx.x, c = threadIdx.x;
  const int n = perm[k];
  const int b = n >> 10, t = n & 1023;
  const float v = x[(size_t)b * (C_ * T_) + (size_t)c * T_ + t];
  ema[((size_t)k << 8) + c] = v;
  emaT[((size_t)c << 10) + k] = v;
  const double s = block_reduce_256_f64((double)v * (double)v, red);
  if (c == 0) { csq[k] = s; csq32[k] = (float)s; }
}

// EMA update: exact f32 reference arithmetic (no fma contraction); validated in R2.
__global__ void update_kernel(float* __restrict__ ema, float* __restrict__ emaT,
                              const double* __restrict__ sums, const int* __restrict__ counts,
                              double* __restrict__ csq, float* __restrict__ csq32) {
  __shared__ double red[4];
  const int k = blockIdx.x, c = threadIdx.x;
  const size_t idx = ((size_t)k << 8) + c;
  const int cnt = counts[k];
  const float e = ema[idx];
  float center;
  if (cnt == 0) {
    center = e;
  } else {
    const float s32 = (float)sums[idx];
    const float denom = __fadd_rn((float)cnt, 1e-5f);
    center = __fdiv_rn(s32, denom);
  }
  const float ne = __fadd_rn(__fmul_rn(e, 0.99f), __fmul_rn(0.01f, center));
  ema[idx] = ne;
  emaT[((size_t)c << 10) + k] = ne;
  const double s = block_reduce_256_f64((double)ne * (double)ne, red);
  if (c == 0) { csq[k] = s; csq32[k] = (float)s; }
}

// ---------------- f32 fused distance+argmin with best2 margin flagging ----------------
// Block: 64 points x all 1024 k. 256 thr = 8 ty (8 pts each) x 32 tx (8 k per 256-k tile).
// Pipelined: load chunk m+1 to regs during compute of chunk m; 2 barriers/iter, 128 iters.
template<int SUMS>
__global__ __launch_bounds__(256, 2) void assign32_kernel(
    const float* __restrict__ x, const float* __restrict__ emaT,
    const float* __restrict__ csq32, int* __restrict__ labels,
    int* __restrict__ flagidx, int* __restrict__ flagcnt,
    double* __restrict__ sums, int* __restrict__ counts) {
  __shared__ float A[C_][64];     // 64 KiB point tile [c][pt]
  __shared__ float Bl[8][256];    // 8 KiB chunk: 8 channels x 256 k
  __shared__ int lab[64];

  const int tid = threadIdx.x;
  const int n0 = blockIdx.x * 64;
  const int b = n0 >> 10, t0 = n0 & 1023;
  const float* xb = x + (size_t)b * (C_ * T_);

  #pragma unroll
  for (int i = 0; i < 16; ++i) {
    const int idx = tid + (i << 8);
    const int cl = idx >> 4, tl = idx & 15;
    *(float4*)&A[cl][tl << 2] = *(const float4*)(xb + (size_t)cl * T_ + t0 + (tl << 2));
  }

  const int ty = tid >> 5;   // point group (8 pts)
  const int tx = tid & 31;   // k lane
  const int sch = tid >> 5, sseg = tid & 31;   // staging: row, 8-float segment

  float4 v0, v1;
  { // chunk 0 (kt=0, cc=0): coalesced from k-major emaT
    const float* p = emaT + (size_t)sch * K_ + (sseg << 3);
    v0 = *(const float4*)p; v1 = *(const float4*)(p + 4);
    *(float4*)&Bl[sch][sseg << 3] = v0;
    *(float4*)&Bl[sch][(sseg << 3) + 4] = v1;
  }
  __syncthreads();

  float bestd[8], best2[8]; int bestk[8];
  #pragma unroll
  for (int i = 0; i < 8; ++i) { bestd[i] = 3.0e38f; best2[i] = 3.0e38f; bestk[i] = 0; }

  float acc[8][8];
  #pragma unroll
  for (int i = 0; i < 8; ++i)
    #pragma unroll
    for (int j = 0; j < 8; ++j) acc[i][j] = 0.f;

  for (int m = 0; m < 128; ++m) {          // m = kt*32 + cc ; kt: 256-k tile, cc: 8-ch chunk
    const int kt = m >> 5, cc = m & 31;
    if (m < 127) {                          // prefetch chunk m+1 into regs
      const int m1 = m + 1;
      const float* p = emaT + (size_t)(((m1 & 31) << 3) + sch) * K_ + ((m1 >> 5) << 8) + (sseg << 3);
      v0 = *(const float4*)p; v1 = *(const float4*)(p + 4);
    }
    const int c0 = cc << 3;
    #pragma unroll
    for (int c = 0; c < 8; ++c) {
      const float4 a0 = *(const float4*)&A[c0 + c][ty << 3];
      const float4 a1 = *(const float4*)&A[c0 + c][(ty << 3) + 4];
      const float aa[8] = {a0.x, a0.y, a0.z, a0.w, a1.x, a1.y, a1.z, a1.w};
      float bb[8];
      #pragma unroll
      for (int jj = 0; jj < 4; ++jj) {
        const float2 bv = *(const float2*)&Bl[c][(tx << 1) + (jj << 6)];
        bb[2 * jj] = bv.x; bb[2 * jj + 1] = bv.y;
      }
      #pragma unroll
      for (int i = 0; i < 8; ++i)
        #pragma unroll
        for (int j = 0; j < 8; ++j)
          acc[i][j] = fmaf(aa[i], bb[j], acc[i][j]);
    }
    if (cc == 31) {                         // k-tile epilogue: fold into best/best2
      const int k0 = kt << 8;
      #pragma unroll
      for (int j = 0; j < 8; ++j) {         // kk ascending within thread -> lowest-k ties
        const int kk = k0 + ((j >> 1) << 6) + (tx << 1) + (j & 1);
        const float cq = csq32[kk];
        #pragma unroll
        for (int i = 0; i < 8; ++i) {
          const float d = fmaf(-2.f, acc[i][j], cq);
          if (d < bestd[i]) { best2[i] = bestd[i]; bestd[i] = d; bestk[i] = kk; }
          else if (d < best2[i]) best2[i] = d;
          acc[i][j] = 0.f;
        }
      }
    }
    __syncthreads();
    if (m < 127) {                          // publish chunk m+1
      *(float4*)&Bl[sch][sseg << 3] = v0;
      *(float4*)&Bl[sch][(sseg << 3) + 4] = v1;
    }
    __syncthreads();
  }

  // reduce (best, bestk, best2) across the 32 tx lanes (bits 0..4, within wave)
  #pragma unroll
  for (int i = 0; i < 8; ++i) {
    #pragma unroll
    for (int s = 1; s < 32; s <<= 1) {
      const float od  = __shfl_xor(bestd[i], s, 64);
      const float ob2 = __shfl_xor(best2[i], s, 64);
      const int   ok  = __shfl_xor(bestk[i], s, 64);
      float nb, nb2; int nk;
      if (od < bestd[i] || (od == bestd[i] && ok < bestk[i])) {
        nb = od; nk = ok; nb2 = fminf(ob2, bestd[i]);
      } else {
        nb = bestd[i]; nk = bestk[i]; nb2 = fminf(best2[i], od);
      }
      bestd[i] = nb; bestk[i] = nk; best2[i] = nb2;
    }
    if (tx == 0) {
      const int pl = (ty << 3) + i;
      const int n = n0 + pl;
      labels[n] = bestk[i];
      lab[pl] = bestk[i];
      if (best2[i] - bestd[i] <= MARGIN_) {   // near-tie: defer to exact refine
        const int p = atomicAdd(flagcnt, 1);
        flagidx[p] = n;
      }
    }
  }

  if (SUMS) {   // segment sums with pre-refine labels; refine patches the changed ones
    __syncthreads();
    if (tid < 64) atomicAdd(&counts[lab[tid]], 1);
    const int cl = tid >> 5, tl = tid & 31;
    #pragma unroll 1
    for (int cc2 = 0; cc2 < 32; ++cc2) {
      const int c = (cc2 << 3) + cl;
      #pragma unroll
      for (int e = 0; e < 2; ++e) {
        const int p = (tl << 1) + e;
        unsafeAtomicAdd(&sums[(((size_t)lab[p]) << 8) + c], (double)A[c][p]);
      }
    }
  }
}

// ---------------- exact f64 refine of flagged points (formula identical to R2 pass) ----
__global__ void refine_kernel(const float* __restrict__ x, const float* __restrict__ ema,
                              const double* __restrict__ csq,
                              const int* __restrict__ flagidx, const int* __restrict__ flagcnt,
                              int* __restrict__ labels, double* __restrict__ sums,
                              int* __restrict__ counts) {
  __shared__ float xr[C_];
  __shared__ double rd[4]; __shared__ int rk[4];
  __shared__ int s_old, s_new;
  const int tid = threadIdx.x;
  const int cnt = *flagcnt;
  for (int it = blockIdx.x; it < cnt; it += gridDim.x) {
    const int n = flagidx[it];
    const int b = n >> 10, t = n & 1023;
    xr[tid] = x[(size_t)b * (C_ * T_) + (size_t)tid * T_ + t];
    __syncthreads();
    double bd = 1e300; int bk = 0;
    #pragma unroll 1
    for (int r = 0; r < 4; ++r) {
      const int k = (r << 8) + tid;
      const float* er = ema + ((size_t)k << 8);
      double acc = 0.0;
      #pragma unroll 4
      for (int c4 = 0; c4 < 64; ++c4) {
        const float4 ev = *(const float4*)(er + (c4 << 2));
        const float4 xv = *(const float4*)(&xr[c4 << 2]);
        acc = fma((double)xv.x, (double)ev.x, acc);
        acc = fma((double)xv.y, (double)ev.y, acc);
        acc = fma((double)xv.z, (double)ev.z, acc);
        acc = fma((double)xv.w, (double)ev.w, acc);
      }
      const double d = csq[k] - 2.0 * acc;
      if (d < bd) { bd = d; bk = k; }       // k ascending per thread
    }
    #pragma unroll
    for (int s = 1; s < 64; s <<= 1) {
      const double od = __shfl_xor(bd, s, 64);
      const int    ok = __shfl_xor(bk, s, 64);
      if (od < bd || (od == bd && ok < bk)) { bd = od; bk = ok; }
    }
    if ((tid & 63) == 0) { rd[tid >> 6] = bd; rk[tid >> 6] = bk; }
    __syncthreads();
    if (tid == 0) {
      #pragma unroll
      for (int w = 1; w < 4; ++w)
        if (rd[w] < bd || (rd[w] == bd && rk[w] < bk)) { bd = rd[w]; bk = rk[w]; }
      s_old = labels[n]; s_new = bk;
      if (bk != s_old) labels[n] = bk;
    }
    __syncthreads();
    if (s_new != s_old && sums != nullptr) {    // patch segment sums for changed label
      const double xv = (double)xr[tid];
      unsafeAtomicAdd(&sums[(((size_t)s_old) << 8) + tid], -xv);
      unsafeAtomicAdd(&sums[(((size_t)s_new) << 8) + tid], xv);
      if (tid == 0) { atomicAdd(&counts[s_old], -1); atomicAdd(&counts[s_new], 1); }
    }
    __syncthreads();
  }
}

// ---------------- launch ----------------
extern "C" void kernel_launch(void* const* d_in, const int* in_sizes, int n_in,
                              void* d_out, int out_size, void* d_ws, size_t ws_size,
                              hipStream_t stream) {
  const float* x = (const float*)d_in[0];
  int* out = (int*)d_out;            // doubles as the labels buffer all along
  char* ws = (char*)d_ws;

  float*  ema   = (float*) (ws + 0);                 // 1 MiB
  float*  emaT  = (float*) (ws + 1048576);           // 1 MiB (k-major transpose)
  double* sums  = (double*)(ws + 2097152);           // 2 MiB
  // sort scratch aliases the sums region (used only before the iterations)
  unsigned long long* keys = (unsigned long long*)(ws + 2097152);   // 256 KiB
  int*    rank  = (int*)   (ws + 2359296);           // 128 KiB
  int*    val1  = (int*)   (ws + 2490368);           // 128 KiB
  int*    counts= (int*)   (ws + 4194304);           // 4 KiB (right after sums)
  double* csq   = (double*)(ws + 4198400);           // 8 KiB
  float*  csq32 = (float*) (ws + 4206592);           // 4 KiB
  int*    perm  = (int*)   (ws + 4210688);           // 4 KiB
  int*    flagidx = (int*) (ws + 4214784);           // 128 KiB
  int*    flagcnt = (int*) (ws + 4345856);           // 4 B

  // host-side threefry: the two per-round sort subkeys from key(1) = (0,1)
  uint32_t s1h, s1l, s2h, s2l;
  {
#if JAX_PARTITIONABLE
    uint32_t ch, cl;
    tf2x32(0u, 1u, 0u, 0u, ch, cl);
    tf2x32(0u, 1u, 0u, 1u, s1h, s1l);
    tf2x32(ch, cl, 0u, 1u, s2h, s2l);
#else
    uint32_t a0, a1, b0, b1, ch, cl;
    tf2x32(0u, 1u, 0u, 2u, a0, a1); tf2x32(0u, 1u, 1u, 3u, b0, b1);
    ch = a0; cl = b0; s1h = a1; s1l = b1;
    tf2x32(ch, cl, 0u, 2u, a0, a1); tf2x32(ch, cl, 1u, 3u, b0, b1);
    s2h = a1; s2l = b1;
#endif
  }

  // stable sort round 1
#if JAX_PARTITIONABLE
  bits_kernel<<<128, 256, 0, stream>>>(s1h, s1l, keys);
#else
  bits_kernel<<<64, 256, 0, stream>>>(s1h, s1l, keys);
#endif
  hipMemsetAsync(rank, 0, N_ * 4, stream);
  rank_kernel<<<dim3(128, 8), 256, 0, stream>>>(keys, rank);
  scatter1_kernel<<<128, 256, 0, stream>>>(rank, val1);

  // stable sort round 2 -> perm
#if JAX_PARTITIONABLE
  bits_kernel<<<128, 256, 0, stream>>>(s2h, s2l, keys);
#else
  bits_kernel<<<64, 256, 0, stream>>>(s2h, s2l, keys);
#endif
  hipMemsetAsync(rank, 0, N_ * 4, stream);
  rank_kernel<<<dim3(128, 8), 256, 0, stream>>>(keys, rank);
  scatter2_kernel<<<128, 256, 0, stream>>>(rank, val1, perm);

  init_ema_kernel<<<K_, 256, 0, stream>>>(x, perm, ema, emaT, csq, csq32);

  for (int it = 0; it < 10; ++it) {
    hipMemsetAsync(sums, 0, (size_t)K_ * C_ * 8 + K_ * 4, stream);  // sums + counts
    hipMemsetAsync(flagcnt, 0, 4, stream);
    assign32_kernel<1><<<512, 256, 0, stream>>>(x, emaT, csq32, out, flagidx, flagcnt, sums, counts);
    refine_kernel<<<512, 256, 0, stream>>>(x, ema, csq, flagidx, flagcnt, out, sums, counts);
    update_kernel<<<K_, 256, 0, stream>>>(ema, emaT, sums, counts, csq, csq32);
  }
  hipMemsetAsync(flagcnt, 0, 4, stream);
  assign32_kernel<0><<<512, 256, 0, stream>>>(x, emaT, csq32, out, flagidx, flagcnt, nullptr, nullptr);
  refine_kernel<<<512, 256, 0, stream>>>(x, ema, csq, flagidx, flagcnt, out, nullptr, nullptr);
}

// Round 4
// 6221.011 us; speedup vs baseline: 1.5272x; 1.3237x over previous
//
#include <hip/hip_runtime.h>
#include <stdint.h>

#define JAX_PARTITIONABLE 1

static constexpr int C_ = 256;
static constexpr int T_ = 1024;
static constexpr int N_ = 32768;   // 32 * 1024
static constexpr int K_ = 1024;
static constexpr float MARGIN_ = 0.02f;  // >> 2x the bf16-split dot error bound (~6e-3)

typedef __attribute__((ext_vector_type(8))) short short8;
typedef __attribute__((ext_vector_type(4))) float f32x4;

// ---------------- Threefry2x32, 20 rounds (JAX-compatible) ----------------
__host__ __device__ __forceinline__ void tf2x32(uint32_t k0, uint32_t k1,
                                                uint32_t x0, uint32_t x1,
                                                uint32_t& o0, uint32_t& o1) {
  const uint32_t ks2 = k0 ^ k1 ^ 0x1BD11BDAu;
  uint32_t v0 = x0 + k0, v1 = x1 + k1;
#define TFR(d) { v0 += v1; v1 = (v1 << d) | (v1 >> (32 - d)); v1 ^= v0; }
#define TF4A TFR(13) TFR(15) TFR(26) TFR(6)
#define TF4B TFR(17) TFR(29) TFR(16) TFR(24)
  TF4A v0 += k1;  v1 += ks2 + 1u;
  TF4B v0 += ks2; v1 += k0 + 2u;
  TF4A v0 += k0;  v1 += k1 + 3u;
  TF4B v0 += k1;  v1 += ks2 + 4u;
  TF4A v0 += ks2; v1 += k0 + 5u;
  o0 = v0; o1 = v1;
#undef TFR
#undef TF4A
#undef TF4B
}

// ---------------- bf16 helpers (RN-even) ----------------
__device__ __forceinline__ uint16_t f2bf(float f) {
  const uint32_t u = __float_as_uint(f);
  return (uint16_t)((u + 0x7FFFu + ((u >> 16) & 1u)) >> 16);
}
__device__ __forceinline__ float bf2f(uint16_t h) {
  return __uint_as_float(((uint32_t)h) << 16);
}

// B-fragment writer: layout [ktile(64)][ck(8)][lane(64)][j(8)] bf16 for
// mfma_f32_16x16x32_bf16 B operand: col=lane&15, k=(lane>>4)*8+j, chunk c-base ck*32.
__device__ __forceinline__ void write_bfrag(uint16_t* __restrict__ bH, uint16_t* __restrict__ bL,
                                            int k, int c, float v) {
  const int kt = k >> 4;
  const int lane = (k & 15) + (((c & 31) >> 3) << 4);
  const int ck = c >> 5;
  const int j = c & 7;
  const uint16_t h = f2bf(v);
  const uint16_t l = f2bf(v - bf2f(h));
  const size_t idx = ((((size_t)(kt << 3) + ck) << 6) + lane) * 8 + j;
  bH[idx] = h; bL[idx] = l;
}

// ---------------- PRNG / permutation kernels (validated R2/R3) ----------------
__global__ void bits_kernel(uint32_t k0, uint32_t k1, unsigned long long* __restrict__ keys) {
#if JAX_PARTITIONABLE
  const int i = blockIdx.x * 256 + threadIdx.x;
  uint32_t o0, o1; tf2x32(k0, k1, 0u, (uint32_t)i, o0, o1);
  keys[i] = (((unsigned long long)(o0 ^ o1)) << 32) | (unsigned)i;
#else
  const int j = blockIdx.x * 256 + threadIdx.x;
  uint32_t o0, o1; tf2x32(k0, k1, (uint32_t)j, (uint32_t)(j + 16384), o0, o1);
  keys[j]         = (((unsigned long long)o0) << 32) | (unsigned)j;
  keys[j + 16384] = (((unsigned long long)o1) << 32) | (unsigned)(j + 16384);
#endif
}

__global__ void rank_kernel(const unsigned long long* __restrict__ keys, int* __restrict__ rank) {
  const int p = blockIdx.x * 256 + threadIdx.x;
  const unsigned long long my = keys[p];
  const int base = blockIdx.y * 4096;
  int cnt = 0;
  #pragma unroll 8
  for (int j = 0; j < 4096; ++j) cnt += (keys[base + j] < my) ? 1 : 0;
  atomicAdd(&rank[p], cnt);
}

__global__ void scatter1_kernel(const int* __restrict__ rank, int* __restrict__ val) {
  const int p = blockIdx.x * 256 + threadIdx.x;
  val[rank[p]] = p;
}

__global__ void scatter2_kernel(const int* __restrict__ rank, const int* __restrict__ val,
                                int* __restrict__ perm) {
  const int q = blockIdx.x * 256 + threadIdx.x;
  const int r = rank[q];
  if (r < K_) perm[r] = val[q];
}

// ---------------- f64 block reduce ----------------
__device__ __forceinline__ double block_reduce_256_f64(double v, double* red) {
  #pragma unroll
  for (int s = 1; s < 64; s <<= 1) v += __shfl_xor(v, s, 64);
  if ((threadIdx.x & 63) == 0) red[threadIdx.x >> 6] = v;
  __syncthreads();
  return red[0] + red[1] + red[2] + red[3];
}

__global__ void init_ema_kernel(const float* __restrict__ x, const int* __restrict__ perm,
                                float* __restrict__ ema, uint16_t* __restrict__ bfH,
                                uint16_t* __restrict__ bfL,
                                double* __restrict__ csq, float* __restrict__ csq32) {
  __shared__ double red[4];
  const int k = blockIdx.x, c = threadIdx.x;
  const int n = perm[k];
  const int b = n >> 10, t = n & 1023;
  const float v = x[(size_t)b * (C_ * T_) + (size_t)c * T_ + t];
  ema[((size_t)k << 8) + c] = v;
  write_bfrag(bfH, bfL, k, c, v);
  const double s = block_reduce_256_f64((double)v * (double)v, red);
  if (c == 0) { csq[k] = s; csq32[k] = (float)s; }
}

// EMA update in exact f32 reference arithmetic (validated R2/R3).
__global__ void update_kernel(float* __restrict__ ema, uint16_t* __restrict__ bfH,
                              uint16_t* __restrict__ bfL,
                              const double* __restrict__ sums, const int* __restrict__ counts,
                              double* __restrict__ csq, float* __restrict__ csq32) {
  __shared__ double red[4];
  const int k = blockIdx.x, c = threadIdx.x;
  const size_t idx = ((size_t)k << 8) + c;
  const int cnt = counts[k];
  const float e = ema[idx];
  float center;
  if (cnt == 0) {
    center = e;
  } else {
    const float s32 = (float)sums[idx];
    const float denom = __fadd_rn((float)cnt, 1e-5f);
    center = __fdiv_rn(s32, denom);
  }
  const float ne = __fadd_rn(__fmul_rn(e, 0.99f), __fmul_rn(0.01f, center));
  ema[idx] = ne;
  write_bfrag(bfH, bfL, k, c, ne);
  const double s = block_reduce_256_f64((double)ne * (double)ne, red);
  if (c == 0) { csq[k] = s; csq32[k] = (float)s; }
}

// ---------------- MFMA assign: bf16-split 3-pass, best2 margin flags ----------------
// Block = 32 points (2 Mtiles of 16), 4 waves. Wave w: k-tiles w*16..w*16+15, groups of 4.
// No barriers in the main loop: A-frags in LDS (read-only), B-frags streamed from global/L2.
template<int SUMS>
__global__ __launch_bounds__(256, 2) void assign_mfma(
    const float* __restrict__ x, const short8* __restrict__ bfH, const short8* __restrict__ bfL,
    const float* __restrict__ csq32, int* __restrict__ labels,
    int* __restrict__ flagidx, int* __restrict__ flagcnt,
    double* __restrict__ sums, int* __restrict__ counts) {
  __shared__ float xstage[C_][32];      // 32 KB f32 tile, kept live for sums scatter
  __shared__ short8 afrag[2][2][8][64]; // [plane H/L][Mtile][ck][lane] : 32 KB
  __shared__ float mg_d[4][32], mg_2[4][32];
  __shared__ int   mg_k[4][32];
  __shared__ int   lab[32];

  const int tid = threadIdx.x;
  const int nt = blockIdx.x;
  const int n0 = nt << 5;
  const int b = n0 >> 10, t0 = n0 & 1023;
  const float* xb = x + (size_t)b * (C_ * T_) + t0;

  // phase 1: coalesced f32 stage
  #pragma unroll
  for (int i = 0; i < 32; ++i) {
    const int idx = tid + (i << 8);
    const int c = idx >> 5, p = idx & 31;
    xstage[c][p] = xb[(size_t)c * T_ + p];
  }
  __syncthreads();

  // phase 2: build A-frags (xh, xl). A layout: row=lane&15, k=(lane>>4)*8+j, c=ck*32+k.
  #pragma unroll
  for (int i = 0; i < 4; ++i) {
    const int slot = tid + (i << 8);          // 0..1023 = mt*512 + ck*64 + lane
    const int lane = slot & 63;
    const int ck = (slot >> 6) & 7;
    const int mt = slot >> 9;
    const int row = lane & 15;
    const int kof = (lane >> 4) << 3;
    short8 h8, l8;
    #pragma unroll
    for (int j = 0; j < 8; ++j) {
      const float v = xstage[(ck << 5) + kof + j][(mt << 4) + row];
      const uint16_t hh = f2bf(v);
      h8[j] = (short)hh;
      l8[j] = (short)f2bf(v - bf2f(hh));
    }
    afrag[0][mt][ck][lane] = h8;
    afrag[1][mt][ck][lane] = l8;
  }
  __syncthreads();

  const int w = tid >> 6, lane = tid & 63;

  float bd[8], b2[8]; int bk[8];
  #pragma unroll
  for (int s = 0; s < 8; ++s) { bd[s] = 3.0e38f; b2[s] = 3.0e38f; bk[s] = 0; }

  const short8* afH = &afrag[0][0][0][0];
  const short8* afL = &afrag[1][0][0][0];

  #pragma unroll 1
  for (int g = 0; g < 4; ++g) {
    f32x4 acc[2][4];
    #pragma unroll
    for (int m = 0; m < 2; ++m)
      #pragma unroll
      for (int t = 0; t < 4; ++t) acc[m][t] = (f32x4){0.f, 0.f, 0.f, 0.f};

    #pragma unroll 1
    for (int pass = 0; pass < 3; ++pass) {
      const short8* ap = (pass == 2) ? afL : afH;       // passes: H*H, H*L, L*H
      const short8* bp = (pass == 1) ? bfL : bfH;
      #pragma unroll 2
      for (int ck = 0; ck < 8; ++ck) {
        const short8 a0 = ap[(ck << 6) + lane];
        const short8 a1 = ap[512 + (ck << 6) + lane];
        const size_t bbase = ((((size_t)(w << 4) + (g << 2)) << 3) + ck) * 64 + lane;
        #pragma unroll
        for (int t = 0; t < 4; ++t) {
          const short8 bf = bp[bbase + (size_t)t * 512];
          acc[0][t] = __builtin_amdgcn_mfma_f32_16x16x32_bf16(a0, bf, acc[0][t], 0, 0, 0);
          acc[1][t] = __builtin_amdgcn_mfma_f32_16x16x32_bf16(a1, bf, acc[1][t], 0, 0, 0);
        }
      }
    }
    // epilogue: D layout col=lane&15, row=(lane>>4)*4+r ; k ascending across g,t
    #pragma unroll
    for (int t = 0; t < 4; ++t) {
      const int kk = (w << 4) + (g << 2) + t;
      const int k = (kk << 4) + (lane & 15);
      const float cq = csq32[k];
      #pragma unroll
      for (int m = 0; m < 2; ++m)
        #pragma unroll
        for (int r = 0; r < 4; ++r) {
          const float d = cq - 2.0f * acc[m][t][r];
          const int s = (m << 2) + r;
          if (d < bd[s]) { b2[s] = bd[s]; bd[s] = d; bk[s] = k; }
          else if (d < b2[s]) b2[s] = d;
        }
    }
  }

  // cross-lane argmin over the 16 cols (lane bits 0..3); lexicographic (d, k)
  #pragma unroll
  for (int s = 0; s < 8; ++s) {
    #pragma unroll
    for (int sh = 1; sh < 16; sh <<= 1) {
      const float od = __shfl_xor(bd[s], sh, 64);
      const float o2 = __shfl_xor(b2[s], sh, 64);
      const int   ok = __shfl_xor(bk[s], sh, 64);
      if (od < bd[s] || (od == bd[s] && ok < bk[s])) {
        b2[s] = fminf(o2, bd[s]); bd[s] = od; bk[s] = ok;
      } else {
        b2[s] = fminf(b2[s], od);
      }
    }
  }
  if ((lane & 15) == 0) {
    #pragma unroll
    for (int s = 0; s < 8; ++s) {
      const int m = s >> 2, r = s & 3;
      const int pt = (m << 4) + ((lane >> 4) << 2) + r;
      mg_d[w][pt] = bd[s]; mg_2[w][pt] = b2[s]; mg_k[w][pt] = bk[s];
    }
  }
  __syncthreads();

  if (tid < 32) {   // merge 4 waves (ascending k-ranges -> ties keep earlier)
    float fb = mg_d[0][tid], f2 = mg_2[0][tid]; int fk = mg_k[0][tid];
    #pragma unroll
    for (int ww = 1; ww < 4; ++ww) {
      const float od = mg_d[ww][tid], o2 = mg_2[ww][tid]; const int ok = mg_k[ww][tid];
      if (od < fb) { f2 = fminf(fb, o2); fb = od; fk = ok; }
      else f2 = fminf(f2, fminf(od, o2));
    }
    const int n = n0 + tid;
    labels[n] = fk;
    lab[tid] = fk;
    if (f2 - fb <= MARGIN_) { const int p = atomicAdd(flagcnt, 1); flagidx[p] = n; }
  }
  __syncthreads();

  if (SUMS) {
    if (tid < 32) atomicAdd(&counts[lab[tid]], 1);
    const int cl = tid >> 5, p = tid & 31;
    #pragma unroll 1
    for (int cc = 0; cc < 32; ++cc) {
      const int c = (cc << 3) + cl;
      unsafeAtomicAdd(&sums[(((size_t)lab[p]) << 8) + c], (double)xstage[c][p]);
    }
  }
}

// ---------------- exact f64 refine of flagged points (validated R2/R3) ----------------
__global__ void refine_kernel(const float* __restrict__ x, const float* __restrict__ ema,
                              const double* __restrict__ csq,
                              const int* __restrict__ flagidx, const int* __restrict__ flagcnt,
                              int* __restrict__ labels, double* __restrict__ sums,
                              int* __restrict__ counts) {
  __shared__ float xr[C_];
  __shared__ double rd[4]; __shared__ int rk[4];
  __shared__ int s_old, s_new;
  const int tid = threadIdx.x;
  const int cnt = *flagcnt;
  for (int it = blockIdx.x; it < cnt; it += gridDim.x) {
    const int n = flagidx[it];
    const int b = n >> 10, t = n & 1023;
    xr[tid] = x[(size_t)b * (C_ * T_) + (size_t)tid * T_ + t];
    __syncthreads();
    double bdv = 1e300; int bkv = 0;
    #pragma unroll 1
    for (int r = 0; r < 4; ++r) {
      const int k = (r << 8) + tid;
      const float* er = ema + ((size_t)k << 8);
      double acc = 0.0;
      #pragma unroll 4
      for (int c4 = 0; c4 < 64; ++c4) {
        const float4 ev = *(const float4*)(er + (c4 << 2));
        const float4 xv = *(const float4*)(&xr[c4 << 2]);
        acc = fma((double)xv.x, (double)ev.x, acc);
        acc = fma((double)xv.y, (double)ev.y, acc);
        acc = fma((double)xv.z, (double)ev.z, acc);
        acc = fma((double)xv.w, (double)ev.w, acc);
      }
      const double d = csq[k] - 2.0 * acc;
      if (d < bdv) { bdv = d; bkv = k; }
    }
    #pragma unroll
    for (int s = 1; s < 64; s <<= 1) {
      const double od = __shfl_xor(bdv, s, 64);
      const int    ok = __shfl_xor(bkv, s, 64);
      if (od < bdv || (od == bdv && ok < bkv)) { bdv = od; bkv = ok; }
    }
    if ((tid & 63) == 0) { rd[tid >> 6] = bdv; rk[tid >> 6] = bkv; }
    __syncthreads();
    if (tid == 0) {
      #pragma unroll
      for (int wv = 1; wv < 4; ++wv)
        if (rd[wv] < bdv || (rd[wv] == bdv && rk[wv] < bkv)) { bdv = rd[wv]; bkv = rk[wv]; }
      s_old = labels[n]; s_new = bkv;
      if (bkv != s_old) labels[n] = bkv;
    }
    __syncthreads();
    if (s_new != s_old && sums != nullptr) {
      const double xv = (double)xr[tid];
      unsafeAtomicAdd(&sums[(((size_t)s_old) << 8) + tid], -xv);
      unsafeAtomicAdd(&sums[(((size_t)s_new) << 8) + tid], xv);
      if (tid == 0) { atomicAdd(&counts[s_old], -1); atomicAdd(&counts[s_new], 1); }
    }
    __syncthreads();
  }
}

// ---------------- launch ----------------
extern "C" void kernel_launch(void* const* d_in, const int* in_sizes, int n_in,
                              void* d_out, int out_size, void* d_ws, size_t ws_size,
                              hipStream_t stream) {
  const float* x = (const float*)d_in[0];
  int* out = (int*)d_out;
  char* ws = (char*)d_ws;

  float*    ema  = (float*)   (ws + 0);          // 1 MiB
  uint16_t* bfH  = (uint16_t*)(ws + 1048576);    // 512 KiB
  uint16_t* bfL  = (uint16_t*)(ws + 1572864);    // 512 KiB
  double*   sums = (double*)  (ws + 2097152);    // 2 MiB
  // sort scratch aliases the sums region (pre-loop only)
  unsigned long long* keys = (unsigned long long*)(ws + 2097152);  // 256 KiB
  int*    rank  = (int*)  (ws + 2359296);        // 128 KiB
  int*    val1  = (int*)  (ws + 2490368);        // 128 KiB
  int*    counts= (int*)  (ws + 4194304);        // 4 KiB (contiguous after sums)
  double* csq   = (double*)(ws + 4198400);       // 8 KiB
  float*  csq32 = (float*) (ws + 4206592);       // 4 KiB
  int*    perm  = (int*)  (ws + 4210688);        // 4 KiB
  int*    flagidx = (int*)(ws + 4214784);        // 128 KiB
  int*    flagcnt = (int*)(ws + 4345856);        // 4 B

  uint32_t s1h, s1l, s2h, s2l;
  {
#if JAX_PARTITIONABLE
    uint32_t ch, cl;
    tf2x32(0u, 1u, 0u, 0u, ch, cl);
    tf2x32(0u, 1u, 0u, 1u, s1h, s1l);
    tf2x32(ch, cl, 0u, 1u, s2h, s2l);
#else
    uint32_t a0, a1, b0, b1, ch, cl;
    tf2x32(0u, 1u, 0u, 2u, a0, a1); tf2x32(0u, 1u, 1u, 3u, b0, b1);
    ch = a0; cl = b0; s1h = a1; s1l = b1;
    tf2x32(ch, cl, 0u, 2u, a0, a1); tf2x32(ch, cl, 1u, 3u, b0, b1);
    s2h = a1; s2l = b1;
#endif
  }

  // stable sort round 1
#if JAX_PARTITIONABLE
  bits_kernel<<<128, 256, 0, stream>>>(s1h, s1l, keys);
#else
  bits_kernel<<<64, 256, 0, stream>>>(s1h, s1l, keys);
#endif
  hipMemsetAsync(rank, 0, N_ * 4, stream);
  rank_kernel<<<dim3(128, 8), 256, 0, stream>>>(keys, rank);
  scatter1_kernel<<<128, 256, 0, stream>>>(rank, val1);

  // stable sort round 2 -> perm
#if JAX_PARTITIONABLE
  bits_kernel<<<128, 256, 0, stream>>>(s2h, s2l, keys);
#else
  bits_kernel<<<64, 256, 0, stream>>>(s2h, s2l, keys);
#endif
  hipMemsetAsync(rank, 0, N_ * 4, stream);
  rank_kernel<<<dim3(128, 8), 256, 0, stream>>>(keys, rank);
  scatter2_kernel<<<128, 256, 0, stream>>>(rank, val1, perm);

  init_ema_kernel<<<K_, 256, 0, stream>>>(x, perm, ema, bfH, bfL, csq, csq32);

  for (int it = 0; it < 10; ++it) {
    hipMemsetAsync(sums, 0, (size_t)K_ * C_ * 8 + K_ * 4, stream);  // sums + counts
    hipMemsetAsync(flagcnt, 0, 4, stream);
    assign_mfma<1><<<1024, 256, 0, stream>>>(x, (const short8*)bfH, (const short8*)bfL,
                                             csq32, out, flagidx, flagcnt, sums, counts);
    refine_kernel<<<512, 256, 0, stream>>>(x, ema, csq, flagidx, flagcnt, out, sums, counts);
    update_kernel<<<K_, 256, 0, stream>>>(ema, bfH, bfL, sums, counts, csq, csq32);
  }
  hipMemsetAsync(flagcnt, 0, 4, stream);
  assign_mfma<0><<<1024, 256, 0, stream>>>(x, (const short8*)bfH, (const short8*)bfL,
                                           csq32, out, flagidx, flagcnt, nullptr, nullptr);
  refine_kernel<<<512, 256, 0, stream>>>(x, ema, csq, flagidx, flagcnt, out, nullptr, nullptr);
}

// Round 5
// 3112.409 us; speedup vs baseline: 3.0526x; 1.9988x over previous
//
#include <hip/hip_runtime.h>
#include <stdint.h>

#define JAX_PARTITIONABLE 1

static constexpr int C_ = 256;
static constexpr int T_ = 1024;
static constexpr int N_ = 32768;   // 32 * 1024
static constexpr int K_ = 1024;
static constexpr float MARGIN_ = 0.02f;  // >> 2x the bf16-split dot error bound (~6e-3)

typedef __attribute__((ext_vector_type(8))) short short8;
typedef __attribute__((ext_vector_type(4))) float f32x4;

// ---------------- Threefry2x32, 20 rounds (JAX-compatible) ----------------
__host__ __device__ __forceinline__ void tf2x32(uint32_t k0, uint32_t k1,
                                                uint32_t x0, uint32_t x1,
                                                uint32_t& o0, uint32_t& o1) {
  const uint32_t ks2 = k0 ^ k1 ^ 0x1BD11BDAu;
  uint32_t v0 = x0 + k0, v1 = x1 + k1;
#define TFR(d) { v0 += v1; v1 = (v1 << d) | (v1 >> (32 - d)); v1 ^= v0; }
#define TF4A TFR(13) TFR(15) TFR(26) TFR(6)
#define TF4B TFR(17) TFR(29) TFR(16) TFR(24)
  TF4A v0 += k1;  v1 += ks2 + 1u;
  TF4B v0 += ks2; v1 += k0 + 2u;
  TF4A v0 += k0;  v1 += k1 + 3u;
  TF4B v0 += k1;  v1 += ks2 + 4u;
  TF4A v0 += ks2; v1 += k0 + 5u;
  o0 = v0; o1 = v1;
#undef TFR
#undef TF4A
#undef TF4B
}

// ---------------- bf16 helpers (RN-even) ----------------
__device__ __forceinline__ uint16_t f2bf(float f) {
  const uint32_t u = __float_as_uint(f);
  return (uint16_t)((u + 0x7FFFu + ((u >> 16) & 1u)) >> 16);
}
__device__ __forceinline__ float bf2f(uint16_t h) {
  return __uint_as_float(((uint32_t)h) << 16);
}

// B-fragment writer: layout [ktile(64)][ck(8)][lane(64)][j(8)] bf16 for
// mfma_f32_16x16x32_bf16 B operand: col=lane&15, k=(lane>>4)*8+j, chunk c-base ck*32.
__device__ __forceinline__ void write_bfrag(uint16_t* __restrict__ bH, uint16_t* __restrict__ bL,
                                            int k, int c, float v) {
  const int kt = k >> 4;
  const int lane = (k & 15) + (((c & 31) >> 3) << 4);
  const int ck = c >> 5;
  const int j = c & 7;
  const uint16_t h = f2bf(v);
  const uint16_t l = f2bf(v - bf2f(h));
  const size_t idx = ((((size_t)(kt << 3) + ck) << 6) + lane) * 8 + j;
  bH[idx] = h; bL[idx] = l;
}

// ---------------- PRNG / permutation kernels (validated R2-R4) ----------------
__global__ void bits_kernel(uint32_t k0, uint32_t k1, unsigned long long* __restrict__ keys) {
#if JAX_PARTITIONABLE
  const int i = blockIdx.x * 256 + threadIdx.x;
  uint32_t o0, o1; tf2x32(k0, k1, 0u, (uint32_t)i, o0, o1);
  keys[i] = (((unsigned long long)(o0 ^ o1)) << 32) | (unsigned)i;
#else
  const int j = blockIdx.x * 256 + threadIdx.x;
  uint32_t o0, o1; tf2x32(k0, k1, (uint32_t)j, (uint32_t)(j + 16384), o0, o1);
  keys[j]         = (((unsigned long long)o0) << 32) | (unsigned)j;
  keys[j + 16384] = (((unsigned long long)o1) << 32) | (unsigned)(j + 16384);
#endif
}

__global__ void rank_kernel(const unsigned long long* __restrict__ keys, int* __restrict__ rank) {
  const int p = blockIdx.x * 256 + threadIdx.x;
  const unsigned long long my = keys[p];
  const int base = blockIdx.y * 4096;
  int cnt = 0;
  #pragma unroll 8
  for (int j = 0; j < 4096; ++j) cnt += (keys[base + j] < my) ? 1 : 0;
  atomicAdd(&rank[p], cnt);
}

__global__ void scatter1_kernel(const int* __restrict__ rank, int* __restrict__ val) {
  const int p = blockIdx.x * 256 + threadIdx.x;
  val[rank[p]] = p;
}

__global__ void scatter2_kernel(const int* __restrict__ rank, const int* __restrict__ val,
                                int* __restrict__ perm) {
  const int q = blockIdx.x * 256 + threadIdx.x;
  const int r = rank[q];
  if (r < K_) perm[r] = val[q];
}

// ---------------- one-time transpose x[b][c][t] -> xT[n][c] ----------------
__global__ void transpose_kernel(const float* __restrict__ x, float* __restrict__ xT) {
  __shared__ float tile[256][33];
  const int tid = threadIdx.x;
  const int b = blockIdx.x >> 5, tt = blockIdx.x & 31;
  const int t0 = tt << 5;
  const float* xb = x + (size_t)b * (C_ * T_) + t0;
  #pragma unroll
  for (int i = 0; i < 32; ++i) {
    const int idx = tid + (i << 8);
    const int c = idx >> 5, p = idx & 31;
    tile[c][p] = xb[(size_t)c * T_ + p];
  }
  __syncthreads();
  float* dst = xT + (((size_t)(b << 10) + t0) << 8);
  #pragma unroll
  for (int p = 0; p < 32; ++p)
    dst[((size_t)p << 8) + tid] = tile[tid][p];
}

// ---------------- f64 block reduce ----------------
__device__ __forceinline__ double block_reduce_256_f64(double v, double* red) {
  #pragma unroll
  for (int s = 1; s < 64; s <<= 1) v += __shfl_xor(v, s, 64);
  if ((threadIdx.x & 63) == 0) red[threadIdx.x >> 6] = v;
  __syncthreads();
  return red[0] + red[1] + red[2] + red[3];
}

__global__ void init_ema_kernel(const float* __restrict__ x, const int* __restrict__ perm,
                                float* __restrict__ ema, uint16_t* __restrict__ bfH,
                                uint16_t* __restrict__ bfL,
                                double* __restrict__ csq, float* __restrict__ csq32) {
  __shared__ double red[4];
  const int k = blockIdx.x, c = threadIdx.x;
  const int n = perm[k];
  const int b = n >> 10, t = n & 1023;
  const float v = x[(size_t)b * (C_ * T_) + (size_t)c * T_ + t];
  ema[((size_t)k << 8) + c] = v;
  write_bfrag(bfH, bfL, k, c, v);
  const double s = block_reduce_256_f64((double)v * (double)v, red);
  if (c == 0) { csq[k] = s; csq32[k] = (float)s; }
}

// EMA update in exact f32 reference arithmetic (validated R2-R4); f64 sums from 4 slices.
__global__ void update_kernel(float* __restrict__ ema, uint16_t* __restrict__ bfH,
                              uint16_t* __restrict__ bfL,
                              const double* __restrict__ sums4, const int* __restrict__ counts,
                              double* __restrict__ csq, float* __restrict__ csq32) {
  __shared__ double red[4];
  const int k = blockIdx.x, c = threadIdx.x;
  const size_t idx = ((size_t)k << 8) + c;
  const int cnt = counts[k];
  const float e = ema[idx];
  float center;
  if (cnt == 0) {
    center = e;
  } else {
    double sd = 0.0;
    #pragma unroll
    for (int sl = 0; sl < 4; ++sl) sd += sums4[((size_t)((sl << 10) + k) << 8) + c];
    const float s32 = (float)sd;
    const float denom = __fadd_rn((float)cnt, 1e-5f);
    center = __fdiv_rn(s32, denom);
  }
  const float ne = __fadd_rn(__fmul_rn(e, 0.99f), __fmul_rn(0.01f, center));
  ema[idx] = ne;
  write_bfrag(bfH, bfL, k, c, ne);
  const double s = block_reduce_256_f64((double)ne * (double)ne, red);
  if (c == 0) { csq[k] = s; csq32[k] = (float)s; }
}

// ---------------- MFMA assign: bf16-split 3-pass, best2 margin flags ----------------
// Block = 32 points (2 Mtiles of 16), 4 waves. Wave w: k-tiles w*16..w*16+15.
// No atomics except flag bump; labels + flags only. LDS ~50 KB -> 3 blocks/CU.
__global__ __launch_bounds__(256, 3) void assign_mfma(
    const float* __restrict__ x, const short8* __restrict__ bfH, const short8* __restrict__ bfL,
    const float* __restrict__ csq32, int* __restrict__ labels,
    int* __restrict__ flagidx, int* __restrict__ flagcnt) {
  __shared__ float xstage[128][33];     // 16.5 KB, reused for both channel halves
  __shared__ short8 afrag[2][2][8][64]; // [plane][Mtile][ck][lane] : 32 KB
  __shared__ float mg_d[4][32], mg_2[4][32];
  __shared__ int   mg_k[4][32];

  const int tid = threadIdx.x;
  const int n0 = blockIdx.x << 5;
  const int b = n0 >> 10, t0 = n0 & 1023;
  const float* xb = x + (size_t)b * (C_ * T_) + t0;

  #pragma unroll
  for (int half = 0; half < 2; ++half) {
    #pragma unroll
    for (int i = 0; i < 16; ++i) {               // stage 128 channels x 32 pts
      const int idx = tid + (i << 8);
      const int c = idx >> 5, p = idx & 31;
      xstage[c][p] = xb[(size_t)((half << 7) + c) * T_ + p];
    }
    __syncthreads();
    #pragma unroll
    for (int i = 0; i < 2; ++i) {                // build A-frags for ck=half*4..half*4+3
      const int slot = tid + (i << 8);           // 0..511 = mt*256 + ck4*64 + lane
      const int lane = slot & 63;
      const int ck4 = (slot >> 6) & 3;
      const int mt = slot >> 8;
      const int row = lane & 15;
      const int kof = (lane >> 4) << 3;
      short8 h8, l8;
      #pragma unroll
      for (int j = 0; j < 8; ++j) {
        const float v = xstage[(ck4 << 5) + kof + j][(mt << 4) + row];
        const uint16_t hh = f2bf(v);
        h8[j] = (short)hh;
        l8[j] = (short)f2bf(v - bf2f(hh));
      }
      afrag[0][mt][(half << 2) + ck4][lane] = h8;
      afrag[1][mt][(half << 2) + ck4][lane] = l8;
    }
    __syncthreads();
  }

  const int w = tid >> 6, lane = tid & 63;

  float bd[8], b2[8]; int bk[8];
  #pragma unroll
  for (int s = 0; s < 8; ++s) { bd[s] = 3.0e38f; b2[s] = 3.0e38f; bk[s] = 0; }

  const short8* afH = &afrag[0][0][0][0];
  const short8* afL = &afrag[1][0][0][0];

  #pragma unroll 1
  for (int g = 0; g < 4; ++g) {
    f32x4 acc[2][4];
    #pragma unroll
    for (int m = 0; m < 2; ++m)
      #pragma unroll
      for (int t = 0; t < 4; ++t) acc[m][t] = (f32x4){0.f, 0.f, 0.f, 0.f};

    #pragma unroll 1
    for (int pass = 0; pass < 3; ++pass) {
      const short8* ap = (pass == 2) ? afL : afH;       // passes: H*H, H*L, L*H
      const short8* bp = (pass == 1) ? bfL : bfH;
      #pragma unroll 2
      for (int ck = 0; ck < 8; ++ck) {
        const short8 a0 = ap[(ck << 6) + lane];
        const short8 a1 = ap[512 + (ck << 6) + lane];
        const size_t bbase = ((((size_t)(w << 4) + (g << 2)) << 3) + ck) * 64 + lane;
        #pragma unroll
        for (int t = 0; t < 4; ++t) {
          const short8 bf = bp[bbase + (size_t)t * 512];
          acc[0][t] = __builtin_amdgcn_mfma_f32_16x16x32_bf16(a0, bf, acc[0][t], 0, 0, 0);
          acc[1][t] = __builtin_amdgcn_mfma_f32_16x16x32_bf16(a1, bf, acc[1][t], 0, 0, 0);
        }
      }
    }
    // epilogue: D layout col=lane&15, row=(lane>>4)*4+r ; k ascending across g,t
    #pragma unroll
    for (int t = 0; t < 4; ++t) {
      const int kk = (w << 4) + (g << 2) + t;
      const int k = (kk << 4) + (lane & 15);
      const float cq = csq32[k];
      #pragma unroll
      for (int m = 0; m < 2; ++m)
        #pragma unroll
        for (int r = 0; r < 4; ++r) {
          const float d = cq - 2.0f * acc[m][t][r];
          const int s = (m << 2) + r;
          if (d < bd[s]) { b2[s] = bd[s]; bd[s] = d; bk[s] = k; }
          else if (d < b2[s]) b2[s] = d;
        }
    }
  }

  // cross-lane argmin over the 16 cols; lexicographic (d, k)
  #pragma unroll
  for (int s = 0; s < 8; ++s) {
    #pragma unroll
    for (int sh = 1; sh < 16; sh <<= 1) {
      const float od = __shfl_xor(bd[s], sh, 64);
      const float o2 = __shfl_xor(b2[s], sh, 64);
      const int   ok = __shfl_xor(bk[s], sh, 64);
      if (od < bd[s] || (od == bd[s] && ok < bk[s])) {
        b2[s] = fminf(o2, bd[s]); bd[s] = od; bk[s] = ok;
      } else {
        b2[s] = fminf(b2[s], od);
      }
    }
  }
  if ((lane & 15) == 0) {
    #pragma unroll
    for (int s = 0; s < 8; ++s) {
      const int m = s >> 2, r = s & 3;
      const int pt = (m << 4) + ((lane >> 4) << 2) + r;
      mg_d[w][pt] = bd[s]; mg_2[w][pt] = b2[s]; mg_k[w][pt] = bk[s];
    }
  }
  __syncthreads();

  if (tid < 32) {   // merge 4 waves (ascending k-ranges -> ties keep earlier)
    float fb = mg_d[0][tid], f2 = mg_2[0][tid]; int fk = mg_k[0][tid];
    #pragma unroll
    for (int ww = 1; ww < 4; ++ww) {
      const float od = mg_d[ww][tid], o2 = mg_2[ww][tid]; const int ok = mg_k[ww][tid];
      if (od < fb) { f2 = fminf(fb, o2); fb = od; fk = ok; }
      else f2 = fminf(f2, fminf(od, o2));
    }
    const int n = n0 + tid;
    labels[n] = fk;
    if (f2 - fb <= MARGIN_) { const int p = atomicAdd(flagcnt, 1); flagidx[p] = n; }
  }
}

// ---------------- exact f64 refine of flagged points (labels only) ----------------
__global__ void refine_kernel(const float* __restrict__ x, const float* __restrict__ ema,
                              const double* __restrict__ csq,
                              const int* __restrict__ flagidx, const int* __restrict__ flagcnt,
                              int* __restrict__ labels) {
  __shared__ float xr[C_];
  __shared__ double rd[4]; __shared__ int rk[4];
  const int tid = threadIdx.x;
  const int cnt = *flagcnt;
  for (int it = blockIdx.x; it < cnt; it += gridDim.x) {
    const int n = flagidx[it];
    const int b = n >> 10, t = n & 1023;
    xr[tid] = x[(size_t)b * (C_ * T_) + (size_t)tid * T_ + t];
    __syncthreads();
    double bdv = 1e300; int bkv = 0;
    #pragma unroll 1
    for (int r = 0; r < 4; ++r) {
      const int k = (r << 8) + tid;
      const float* er = ema + ((size_t)k << 8);
      double acc = 0.0;
      #pragma unroll 4
      for (int c4 = 0; c4 < 64; ++c4) {
        const float4 ev = *(const float4*)(er + (c4 << 2));
        const float4 xv = *(const float4*)(&xr[c4 << 2]);
        acc = fma((double)xv.x, (double)ev.x, acc);
        acc = fma((double)xv.y, (double)ev.y, acc);
        acc = fma((double)xv.z, (double)ev.z, acc);
        acc = fma((double)xv.w, (double)ev.w, acc);
      }
      const double d = csq[k] - 2.0 * acc;
      if (d < bdv) { bdv = d; bkv = k; }
    }
    #pragma unroll
    for (int s = 1; s < 64; s <<= 1) {
      const double od = __shfl_xor(bdv, s, 64);
      const int    ok = __shfl_xor(bkv, s, 64);
      if (od < bdv || (od == bdv && ok < bkv)) { bdv = od; bkv = ok; }
    }
    if ((tid & 63) == 0) { rd[tid >> 6] = bdv; rk[tid >> 6] = bkv; }
    __syncthreads();
    if (tid == 0) {
      #pragma unroll
      for (int wv = 1; wv < 4; ++wv)
        if (rd[wv] < bdv || (rd[wv] == bdv && rk[wv] < bkv)) { bdv = rd[wv]; bkv = rk[wv]; }
      if (bkv != labels[n]) labels[n] = bkv;
    }
    __syncthreads();
  }
}

// ---------------- deterministic segment sums: hist -> prefix -> sort -> gather ----------
__global__ void hist_kernel(const int* __restrict__ labels, int* __restrict__ counts) {
  const int n = blockIdx.x * 256 + threadIdx.x;
  atomicAdd(&counts[labels[n]], 1);
}

__global__ void prefix_kernel(const int* __restrict__ counts, int* __restrict__ offsets,
                              int* __restrict__ cursor) {
  __shared__ int part[256];
  __shared__ int pre[256];
  const int tid = threadIdx.x;
  int v[4]; int s = 0;
  #pragma unroll
  for (int i = 0; i < 4; ++i) { v[i] = counts[(tid << 2) + i]; s += v[i]; }
  part[tid] = s;
  __syncthreads();
  if (tid == 0) { int run = 0; for (int i = 0; i < 256; ++i) { pre[i] = run; run += part[i]; } }
  __syncthreads();
  int run = pre[tid];
  #pragma unroll
  for (int i = 0; i < 4; ++i) {
    offsets[(tid << 2) + i] = run; cursor[(tid << 2) + i] = run; run += v[i];
  }
}

__global__ void scatter_sorted_kernel(const int* __restrict__ labels, int* __restrict__ cursor,
                                      int* __restrict__ sortedIdx) {
  const int n = blockIdx.x * 256 + threadIdx.x;
  const int pos = atomicAdd(&cursor[labels[n]], 1);
  sortedIdx[pos] = n;
}

// block = (k, slice of 4); thread = channel. Non-atomic f64 partial sums.
template<int TRANS>
__global__ void segsum_kernel(const float* __restrict__ x, const float* __restrict__ xT,
                              const int* __restrict__ sortedIdx, const int* __restrict__ offsets,
                              const int* __restrict__ counts, double* __restrict__ sums4) {
  const int k = blockIdx.x >> 2, sl = blockIdx.x & 3;
  const int tid = threadIdx.x;
  const int cnt = counts[k], off = offsets[k];
  const int i0 = (cnt * sl) >> 2, i1 = (cnt * (sl + 1)) >> 2;
  double acc = 0.0;
  int i = i0;
  for (; i + 4 <= i1; i += 4) {
    float v0, v1, v2, v3;
    if (TRANS) {
      const int na = sortedIdx[off + i],     nb = sortedIdx[off + i + 1];
      const int nc = sortedIdx[off + i + 2], nd = sortedIdx[off + i + 3];
      v0 = xT[((size_t)na << 8) + tid]; v1 = xT[((size_t)nb << 8) + tid];
      v2 = xT[((size_t)nc << 8) + tid]; v3 = xT[((size_t)nd << 8) + tid];
    } else {
      const int na = sortedIdx[off + i],     nb = sortedIdx[off + i + 1];
      const int nc = sortedIdx[off + i + 2], nd = sortedIdx[off + i + 3];
      v0 = x[(size_t)(na >> 10) * (C_ * T_) + (size_t)tid * T_ + (na & 1023)];
      v1 = x[(size_t)(nb >> 10) * (C_ * T_) + (size_t)tid * T_ + (nb & 1023)];
      v2 = x[(size_t)(nc >> 10) * (C_ * T_) + (size_t)tid * T_ + (nc & 1023)];
      v3 = x[(size_t)(nd >> 10) * (C_ * T_) + (size_t)tid * T_ + (nd & 1023)];
    }
    acc += (double)v0; acc += (double)v1; acc += (double)v2; acc += (double)v3;
  }
  for (; i < i1; ++i) {
    const int n = sortedIdx[off + i];
    const float v = TRANS ? xT[((size_t)n << 8) + tid]
                          : x[(size_t)(n >> 10) * (C_ * T_) + (size_t)tid * T_ + (n & 1023)];
    acc += (double)v;
  }
  sums4[((size_t)((sl << 10) + k) << 8) + tid] = acc;
}

// ---------------- launch ----------------
extern "C" void kernel_launch(void* const* d_in, const int* in_sizes, int n_in,
                              void* d_out, int out_size, void* d_ws, size_t ws_size,
                              hipStream_t stream) {
  const float* x = (const float*)d_in[0];
  int* out = (int*)d_out;
  char* ws = (char*)d_ws;

  float*    ema   = (float*)   (ws + 0);             // 1 MiB
  uint16_t* bfH   = (uint16_t*)(ws + 1048576);       // 512 KiB
  uint16_t* bfL   = (uint16_t*)(ws + 1572864);       // 512 KiB
  double*   sums4 = (double*)  (ws + 2097152);       // 8 MiB [4][K][C]
  // sort scratch aliases the sums4 region (pre-loop only)
  unsigned long long* keys = (unsigned long long*)(ws + 2097152);  // 256 KiB
  int*    rank   = (int*)  (ws + 2359296);           // 128 KiB
  int*    val1   = (int*)  (ws + 2490368);           // 128 KiB
  const size_t MISC = 2097152 + 8388608;             // 10 MiB
  int*    counts  = (int*)  (ws + MISC);             // 4 KiB
  int*    offsets = (int*)  (ws + MISC + 4096);      // 4 KiB
  int*    cursor  = (int*)  (ws + MISC + 8192);      // 4 KiB
  double* csq     = (double*)(ws + MISC + 12288);    // 8 KiB
  float*  csq32   = (float*) (ws + MISC + 20480);    // 4 KiB
  int*    perm    = (int*)  (ws + MISC + 24576);     // 4 KiB
  int*    flagcnt = (int*)  (ws + MISC + 28672);     // 4 KiB (4 B used)
  int*    flagidx = (int*)  (ws + MISC + 32768);     // 128 KiB
  int*    sortedIdx = (int*)(ws + MISC + 163840);    // 128 KiB
  const size_t XT_OFF = 11534336;                    // 11 MiB
  float*  xT      = (float*) (ws + XT_OFF);          // 32 MiB
  const bool trans_ok = ws_size >= XT_OFF + (size_t)N_ * C_ * 4;

  uint32_t s1h, s1l, s2h, s2l;
  {
#if JAX_PARTITIONABLE
    uint32_t ch, cl;
    tf2x32(0u, 1u, 0u, 0u, ch, cl);
    tf2x32(0u, 1u, 0u, 1u, s1h, s1l);
    tf2x32(ch, cl, 0u, 1u, s2h, s2l);
#else
    uint32_t a0, a1, b0, b1, ch, cl;
    tf2x32(0u, 1u, 0u, 2u, a0, a1); tf2x32(0u, 1u, 1u, 3u, b0, b1);
    ch = a0; cl = b0; s1h = a1; s1l = b1;
    tf2x32(ch, cl, 0u, 2u, a0, a1); tf2x32(ch, cl, 1u, 3u, b0, b1);
    s2h = a1; s2l = b1;
#endif
  }

  // stable sort round 1
#if JAX_PARTITIONABLE
  bits_kernel<<<128, 256, 0, stream>>>(s1h, s1l, keys);
#else
  bits_kernel<<<64, 256, 0, stream>>>(s1h, s1l, keys);
#endif
  hipMemsetAsync(rank, 0, N_ * 4, stream);
  rank_kernel<<<dim3(128, 8), 256, 0, stream>>>(keys, rank);
  scatter1_kernel<<<128, 256, 0, stream>>>(rank, val1);

  // stable sort round 2 -> perm
#if JAX_PARTITIONABLE
  bits_kernel<<<128, 256, 0, stream>>>(s2h, s2l, keys);
#else
  bits_kernel<<<64, 256, 0, stream>>>(s2h, s2l, keys);
#endif
  hipMemsetAsync(rank, 0, N_ * 4, stream);
  rank_kernel<<<dim3(128, 8), 256, 0, stream>>>(keys, rank);
  scatter2_kernel<<<128, 256, 0, stream>>>(rank, val1, perm);

  init_ema_kernel<<<K_, 256, 0, stream>>>(x, perm, ema, bfH, bfL, csq, csq32);
  if (trans_ok) transpose_kernel<<<1024, 256, 0, stream>>>(x, xT);

  for (int it = 0; it < 10; ++it) {
    hipMemsetAsync(counts, 0, K_ * 4, stream);
    hipMemsetAsync(flagcnt, 0, 4, stream);
    assign_mfma<<<1024, 256, 0, stream>>>(x, (const short8*)bfH, (const short8*)bfL,
                                          csq32, out, flagidx, flagcnt);
    refine_kernel<<<512, 256, 0, stream>>>(x, ema, csq, flagidx, flagcnt, out);
    hist_kernel<<<128, 256, 0, stream>>>(out, counts);
    prefix_kernel<<<1, 256, 0, stream>>>(counts, offsets, cursor);
    scatter_sorted_kernel<<<128, 256, 0, stream>>>(out, cursor, sortedIdx);
    if (trans_ok)
      segsum_kernel<1><<<4096, 256, 0, stream>>>(x, xT, sortedIdx, offsets, counts, sums4);
    else
      segsum_kernel<0><<<4096, 256, 0, stream>>>(x, xT, sortedIdx, offsets, counts, sums4);
    update_kernel<<<K_, 256, 0, stream>>>(ema, bfH, bfL, sums4, counts, csq, csq32);
  }
  hipMemsetAsync(flagcnt, 0, 4, stream);
  assign_mfma<<<1024, 256, 0, stream>>>(x, (const short8*)bfH, (const short8*)bfL,
                                        csq32, out, flagidx, flagcnt);
  refine_kernel<<<512, 256, 0, stream>>>(x, ema, csq, flagidx, flagcnt, out);
}

// Round 7
// 3073.331 us; speedup vs baseline: 3.0914x; 1.0127x over previous
//
#include <hip/hip_runtime.h>
#include <stdint.h>

#define JAX_PARTITIONABLE 1

static constexpr int C_ = 256;
static constexpr int T_ = 1024;
static constexpr int N_ = 32768;   // 32 * 1024
static constexpr int K_ = 1024;
static constexpr float MARGIN_ = 0.02f;  // >> 2x the bf16-split dot error bound (~6e-3)

typedef __attribute__((ext_vector_type(8))) short short8;
typedef __attribute__((ext_vector_type(4))) float f32x4;

// ---------------- Threefry2x32, 20 rounds (JAX-compatible) ----------------
__host__ __device__ __forceinline__ void tf2x32(uint32_t k0, uint32_t k1,
                                                uint32_t x0, uint32_t x1,
                                                uint32_t& o0, uint32_t& o1) {
  const uint32_t ks2 = k0 ^ k1 ^ 0x1BD11BDAu;
  uint32_t v0 = x0 + k0, v1 = x1 + k1;
#define TFR(d) { v0 += v1; v1 = (v1 << d) | (v1 >> (32 - d)); v1 ^= v0; }
#define TF4A TFR(13) TFR(15) TFR(26) TFR(6)
#define TF4B TFR(17) TFR(29) TFR(16) TFR(24)
  TF4A v0 += k1;  v1 += ks2 + 1u;
  TF4B v0 += ks2; v1 += k0 + 2u;
  TF4A v0 += k0;  v1 += k1 + 3u;
  TF4B v0 += k1;  v1 += ks2 + 4u;
  TF4A v0 += ks2; v1 += k0 + 5u;
  o0 = v0; o1 = v1;
#undef TFR
#undef TF4A
#undef TF4B
}

// ---------------- bf16 helpers (RN-even) ----------------
__device__ __forceinline__ uint16_t f2bf(float f) {
  const uint32_t u = __float_as_uint(f);
  return (uint16_t)((u + 0x7FFFu + ((u >> 16) & 1u)) >> 16);
}
__device__ __forceinline__ float bf2f(uint16_t h) {
  return __uint_as_float(((uint32_t)h) << 16);
}

// B-fragment writer: layout [ktile(64)][ck(8)][lane(64)][j(8)] bf16 for
// mfma_f32_16x16x32_bf16 B operand: col=lane&15, k=(lane>>4)*8+j, chunk c-base ck*32.
__device__ __forceinline__ void write_bfrag(uint16_t* __restrict__ bH, uint16_t* __restrict__ bL,
                                            int k, int c, float v) {
  const int kt = k >> 4;
  const int lane = (k & 15) + (((c & 31) >> 3) << 4);
  const int ck = c >> 5;
  const int j = c & 7;
  const uint16_t h = f2bf(v);
  const uint16_t l = f2bf(v - bf2f(h));
  const size_t idx = ((((size_t)(kt << 3) + ck) << 6) + lane) * 8 + j;
  bH[idx] = h; bL[idx] = l;
}

// ---------------- PRNG bits (validated R2-R5) ----------------
__global__ void bits_kernel(uint32_t k0, uint32_t k1, unsigned long long* __restrict__ keys) {
#if JAX_PARTITIONABLE
  const int i = blockIdx.x * 256 + threadIdx.x;
  uint32_t o0, o1; tf2x32(k0, k1, 0u, (uint32_t)i, o0, o1);
  keys[i] = (((unsigned long long)(o0 ^ o1)) << 32) | (unsigned)i;
#else
  const int j = blockIdx.x * 256 + threadIdx.x;
  uint32_t o0, o1; tf2x32(k0, k1, (uint32_t)j, (uint32_t)(j + 16384), o0, o1);
  keys[j]         = (((unsigned long long)o0) << 32) | (unsigned)j;
  keys[j + 16384] = (((unsigned long long)o1) << 32) | (unsigned)(j + 16384);
#endif
}

// ---------------- bucketed stable rank (replaces O(N^2) rank_kernel) ----------------
// Exact stable-sort position: keys all distinct; rank = bucket_off + #{smaller in bucket}.
// Bucket-scatter order is non-deterministic but bucket CONTENT is a set -> rank exact.
__global__ void bhist_kernel(const unsigned long long* __restrict__ keys, int* __restrict__ bcnt) {
  const int i = blockIdx.x * 256 + threadIdx.x;
  atomicAdd(&bcnt[(int)(keys[i] >> 56)], 1);
}

__global__ void bscan_kernel(const int* __restrict__ bcnt, int* __restrict__ boff,
                             int* __restrict__ bcur) {
  if (threadIdx.x == 0) {
    int run = 0;
    for (int i = 0; i < 256; ++i) { boff[i] = run; bcur[i] = run; run += bcnt[i]; }
    boff[256] = run;
  }
}

__global__ void bscatter_kernel(const unsigned long long* __restrict__ keys,
                                int* __restrict__ bcur, unsigned long long* __restrict__ barr) {
  const int i = blockIdx.x * 256 + threadIdx.x;
  const unsigned long long k = keys[i];
  const int pos = atomicAdd(&bcur[(int)(k >> 56)], 1);
  barr[pos] = k;
}

template<int ROUND>
__global__ void brank_kernel(const unsigned long long* __restrict__ barr,
                             const int* __restrict__ boff,
                             int* __restrict__ val1, int* __restrict__ perm) {
  const int i = blockIdx.x * 256 + threadIdx.x;
  const unsigned long long my = barr[i];
  const int b = (int)(my >> 56);
  const int lo = boff[b], hi = boff[b + 1];
  int cnt = 0;
  #pragma unroll 4
  for (int j = lo; j < hi; ++j) cnt += (barr[j] < my) ? 1 : 0;
  const int r = lo + cnt;
  const int idx = (int)(uint32_t)my;    // low 32 bits = original position
  if (ROUND == 1) {
    val1[r] = idx;
  } else {
    if (r < K_) perm[r] = val1[idx];
  }
}

// ---------------- one-time transpose x[b][c][t] -> xT[n][c] ----------------
__global__ void transpose_kernel(const float* __restrict__ x, float* __restrict__ xT) {
  __shared__ float tile[256][33];
  const int tid = threadIdx.x;
  const int b = blockIdx.x >> 5, tt = blockIdx.x & 31;
  const int t0 = tt << 5;
  const float* xb = x + (size_t)b * (C_ * T_) + t0;
  #pragma unroll
  for (int i = 0; i < 32; ++i) {
    const int idx = tid + (i << 8);
    const int c = idx >> 5, p = idx & 31;
    tile[c][p] = xb[(size_t)c * T_ + p];
  }
  __syncthreads();
  float* dst = xT + (((size_t)(b << 10) + t0) << 8);
  #pragma unroll
  for (int p = 0; p < 32; ++p)
    dst[((size_t)p << 8) + tid] = tile[tid][p];
}

// ---------------- f64 block reduce ----------------
__device__ __forceinline__ double block_reduce_256_f64(double v, double* red) {
  #pragma unroll
  for (int s = 1; s < 64; s <<= 1) v += __shfl_xor(v, s, 64);
  if ((threadIdx.x & 63) == 0) red[threadIdx.x >> 6] = v;
  __syncthreads();
  return red[0] + red[1] + red[2] + red[3];
}

__global__ void init_ema_kernel(const float* __restrict__ x, const int* __restrict__ perm,
                                float* __restrict__ ema, uint16_t* __restrict__ bfH,
                                uint16_t* __restrict__ bfL,
                                double* __restrict__ csq, float* __restrict__ csq32) {
  __shared__ double red[4];
  const int k = blockIdx.x, c = threadIdx.x;
  const int n = perm[k];
  const int b = n >> 10, t = n & 1023;
  const float v = x[(size_t)b * (C_ * T_) + (size_t)c * T_ + t];
  ema[((size_t)k << 8) + c] = v;
  write_bfrag(bfH, bfL, k, c, v);
  const double s = block_reduce_256_f64((double)v * (double)v, red);
  if (c == 0) { csq[k] = s; csq32[k] = (float)s; }
}

// EMA update in exact f32 reference arithmetic (validated R2-R5); f64 sums from 4 slices.
__global__ void update_kernel(float* __restrict__ ema, uint16_t* __restrict__ bfH,
                              uint16_t* __restrict__ bfL,
                              const double* __restrict__ sums4, const int* __restrict__ counts,
                              double* __restrict__ csq, float* __restrict__ csq32) {
  __shared__ double red[4];
  const int k = blockIdx.x, c = threadIdx.x;
  const size_t idx = ((size_t)k << 8) + c;
  const int cnt = counts[k];
  const float e = ema[idx];
  float center;
  if (cnt == 0) {
    center = e;
  } else {
    double sd = 0.0;
    #pragma unroll
    for (int sl = 0; sl < 4; ++sl) sd += sums4[((size_t)((sl << 10) + k) << 8) + c];
    const float s32 = (float)sd;
    const float denom = __fadd_rn((float)cnt, 1e-5f);
    center = __fdiv_rn(s32, denom);
  }
  const float ne = __fadd_rn(__fmul_rn(e, 0.99f), __fmul_rn(0.01f, center));
  ema[idx] = ne;
  write_bfrag(bfH, bfL, k, c, ne);
  const double s = block_reduce_256_f64((double)ne * (double)ne, red);
  if (c == 0) { csq[k] = s; csq32[k] = (float)s; }
}

// ---------------- MFMA assign: 64 pts/block, bf16-split 3-pass, best2 margin flags ----
// Block = 64 points (4 Mtiles of 16), 4 waves; wave w owns k-range w*256..w*256+255.
// LDS exactly 80 KB -> 2 blocks/CU. B-frags streamed from L2 (2 MB arrays, XCD-resident).
#define AF(pl, mt, ck, lane) (((((((pl) << 2) + (mt)) << 3) + (ck)) << 6) + (lane))
__global__ __launch_bounds__(256, 2) void assign_mfma(
    const float* __restrict__ x, const short8* __restrict__ bfH, const short8* __restrict__ bfL,
    const float* __restrict__ csq32, int* __restrict__ labels,
    int* __restrict__ flagidx, int* __restrict__ flagcnt) {
  __shared__ __align__(16) char smem[81920];
  short8* afrag = (short8*)smem;                        // [2][4][8][64] : 64 KB
  float (*xstage)[64] = (float(*)[64])(smem + 65536);   // [64][64] : 16 KB (prologue only)
  float* mg_d = (float*)(smem + 65536);                 // [4][64] (reused after prologue)
  float* mg_2 = mg_d + 256;
  int*   mg_k = (int*)(mg_2 + 256);

  const int tid = threadIdx.x;
  const int n0 = blockIdx.x << 6;
  const int b = n0 >> 10, t0 = n0 & 1023;
  const float* xb = x + (size_t)b * (C_ * T_) + t0;

  // prologue: 4 quarters of 64 channels; stage f32 then build A-frags (H,L planes)
  #pragma unroll 1
  for (int q = 0; q < 4; ++q) {
    #pragma unroll
    for (int i = 0; i < 16; ++i) {
      const int idx = tid + (i << 8);
      const int c = idx >> 6, p = idx & 63;
      xstage[c][p] = xb[(size_t)((q << 6) + c) * T_ + p];
    }
    __syncthreads();
    #pragma unroll
    for (int i = 0; i < 2; ++i) {
      const int slot = tid + (i << 8);       // 0..511 = mt*128 + ckh*64 + lane
      const int lane = slot & 63;
      const int ckh = (slot >> 6) & 1;
      const int mt = slot >> 7;
      const int row = lane & 15;
      const int kof = (lane >> 4) << 3;
      short8 h8, l8;
      #pragma unroll
      for (int j = 0; j < 8; ++j) {
        const float v = xstage[(ckh << 5) + kof + j][(mt << 4) + row];
        const uint16_t hh = f2bf(v);
        h8[j] = (short)hh;
        l8[j] = (short)f2bf(v - bf2f(hh));
      }
      const int ck = (q << 1) + ckh;
      afrag[AF(0, mt, ck, lane)] = h8;
      afrag[AF(1, mt, ck, lane)] = l8;
    }
    __syncthreads();
  }

  const int w = tid >> 6, lane = tid & 63;

  float bd[16], b2[16]; int bk[16];
  #pragma unroll
  for (int s = 0; s < 16; ++s) { bd[s] = 3.0e38f; b2[s] = 3.0e38f; bk[s] = 0; }

  const short8* afH = afrag;           // plane 0
  const short8* afL = afrag + 2048;    // plane 1

  #pragma unroll 1
  for (int g = 0; g < 4; ++g) {
    f32x4 acc[4][4];
    #pragma unroll
    for (int mt = 0; mt < 4; ++mt)
      #pragma unroll
      for (int t = 0; t < 4; ++t) acc[mt][t] = (f32x4){0.f, 0.f, 0.f, 0.f};

    #pragma unroll 1
    for (int pass = 0; pass < 3; ++pass) {
      const short8* ap = (pass == 2) ? afL : afH;       // passes: H*H, H*L, L*H
      const short8* bp = (pass == 1) ? bfL : bfH;
      #pragma unroll 2
      for (int ck = 0; ck < 8; ++ck) {
        short8 a0 = ap[(0 << 9) + (ck << 6) + lane];
        short8 a1 = ap[(1 << 9) + (ck << 6) + lane];
        short8 a2 = ap[(2 << 9) + (ck << 6) + lane];
        short8 a3 = ap[(3 << 9) + (ck << 6) + lane];
        const size_t bbase = ((((size_t)(w << 4) + (g << 2)) << 3) + ck) * 64 + lane;
        #pragma unroll
        for (int t = 0; t < 4; ++t) {
          const short8 bf = bp[bbase + (size_t)t * 512];
          acc[0][t] = __builtin_amdgcn_mfma_f32_16x16x32_bf16(a0, bf, acc[0][t], 0, 0, 0);
          acc[1][t] = __builtin_amdgcn_mfma_f32_16x16x32_bf16(a1, bf, acc[1][t], 0, 0, 0);
          acc[2][t] = __builtin_amdgcn_mfma_f32_16x16x32_bf16(a2, bf, acc[2][t], 0, 0, 0);
          acc[3][t] = __builtin_amdgcn_mfma_f32_16x16x32_bf16(a3, bf, acc[3][t], 0, 0, 0);
        }
      }
    }
    // epilogue: D layout col=lane&15 (k), row=(lane>>4)*4+r (point); k ascending in g,t
    #pragma unroll
    for (int t = 0; t < 4; ++t) {
      const int kt = (w << 4) + (g << 2) + t;
      const int k = (kt << 4) + (lane & 15);
      const float cq = csq32[k];
      #pragma unroll
      for (int mt = 0; mt < 4; ++mt)
        #pragma unroll
        for (int r = 0; r < 4; ++r) {
          const float d = cq - 2.0f * acc[mt][t][r];
          const int s = (mt << 2) + r;
          if (d < bd[s]) { b2[s] = bd[s]; bd[s] = d; bk[s] = k; }
          else if (d < b2[s]) b2[s] = d;
        }
    }
  }

  // cross-lane argmin over the 16 k-cols (lane bits 0..3); lexicographic (d, k)
  #pragma unroll
  for (int s = 0; s < 16; ++s) {
    #pragma unroll
    for (int sh = 1; sh < 16; sh <<= 1) {
      const float od = __shfl_xor(bd[s], sh, 64);
      const float o2 = __shfl_xor(b2[s], sh, 64);
      const int   ok = __shfl_xor(bk[s], sh, 64);
      if (od < bd[s] || (od == bd[s] && ok < bk[s])) {
        b2[s] = fminf(o2, bd[s]); bd[s] = od; bk[s] = ok;
      } else {
        b2[s] = fminf(b2[s], od);
      }
    }
  }
  if ((lane & 15) == 0) {
    #pragma unroll
    for (int s = 0; s < 16; ++s) {
      const int mt = s >> 2, r = s & 3;
      const int pt = (mt << 4) + ((lane >> 4) << 2) + r;
      mg_d[(w << 6) + pt] = bd[s]; mg_2[(w << 6) + pt] = b2[s]; mg_k[(w << 6) + pt] = bk[s];
    }
  }
  __syncthreads();

  if (tid < 64) {   // merge 4 waves (ascending k-ranges -> ties keep earlier)
    float fb = mg_d[tid], f2 = mg_2[tid]; int fk = mg_k[tid];
    #pragma unroll
    for (int ww = 1; ww < 4; ++ww) {
      const float od = mg_d[(ww << 6) + tid], o2 = mg_2[(ww << 6) + tid];
      const int ok = mg_k[(ww << 6) + tid];
      if (od < fb) { f2 = fminf(fb, o2); fb = od; fk = ok; }
      else f2 = fminf(f2, fminf(od, o2));
    }
    const int n = n0 + tid;
    labels[n] = fk;
    if (f2 - fb <= MARGIN_) { const int p = atomicAdd(flagcnt, 1); flagidx[p] = n; }
  }
}

// ---------------- exact f64 refine of flagged points (labels only) ----------------
__global__ void refine_kernel(const float* __restrict__ x, const float* __restrict__ ema,
                              const double* __restrict__ csq,
                              const int* __restrict__ flagidx, const int* __restrict__ flagcnt,
                              int* __restrict__ labels) {
  __shared__ float xr[C_];
  __shared__ double rd[4]; __shared__ int rk[4];
  const int tid = threadIdx.x;
  const int cnt = *flagcnt;
  for (int it = blockIdx.x; it < cnt; it += gridDim.x) {
    const int n = flagidx[it];
    const int b = n >> 10, t = n & 1023;
    xr[tid] = x[(size_t)b * (C_ * T_) + (size_t)tid * T_ + t];
    __syncthreads();
    double bdv = 1e300; int bkv = 0;
    #pragma unroll 1
    for (int r = 0; r < 4; ++r) {
      const int k = (r << 8) + tid;
      const float* er = ema + ((size_t)k << 8);
      double acc = 0.0;
      #pragma unroll 4
      for (int c4 = 0; c4 < 64; ++c4) {
        const float4 ev = *(const float4*)(er + (c4 << 2));
        const float4 xv = *(const float4*)(&xr[c4 << 2]);
        acc = fma((double)xv.x, (double)ev.x, acc);
        acc = fma((double)xv.y, (double)ev.y, acc);
        acc = fma((double)xv.z, (double)ev.z, acc);
        acc = fma((double)xv.w, (double)ev.w, acc);
      }
      const double d = csq[k] - 2.0 * acc;
      if (d < bdv) { bdv = d; bkv = k; }
    }
    #pragma unroll
    for (int s = 1; s < 64; s <<= 1) {
      const double od = __shfl_xor(bdv, s, 64);
      const int    ok = __shfl_xor(bkv, s, 64);
      if (od < bdv || (od == bdv && ok < bkv)) { bdv = od; bkv = ok; }
    }
    if ((tid & 63) == 0) { rd[tid >> 6] = bdv; rk[tid >> 6] = bkv; }
    __syncthreads();
    if (tid == 0) {
      #pragma unroll
      for (int wv = 1; wv < 4; ++wv)
        if (rd[wv] < bdv || (rd[wv] == bdv && rk[wv] < bkv)) { bdv = rd[wv]; bkv = rk[wv]; }
      if (bkv != labels[n]) labels[n] = bkv;
    }
    __syncthreads();
  }
}

// ---------------- deterministic segment sums: hist -> prefix -> sort -> gather ----------
__global__ void hist_kernel(const int* __restrict__ labels, int* __restrict__ counts) {
  const int n = blockIdx.x * 256 + threadIdx.x;
  atomicAdd(&counts[labels[n]], 1);
}

__global__ void prefix_kernel(const int* __restrict__ counts, int* __restrict__ offsets,
                              int* __restrict__ cursor) {
  __shared__ int wsum[4];
  const int tid = threadIdx.x;
  const int lane = tid & 63, w = tid >> 6;
  const int c0 = counts[(tid << 2)], c1 = counts[(tid << 2) + 1];
  const int c2 = counts[(tid << 2) + 2], c3 = counts[(tid << 2) + 3];
  const int s = c0 + c1 + c2 + c3;
  int inc = s;
  #pragma unroll
  for (int sh = 1; sh < 64; sh <<= 1) {
    const int t = __shfl_up(inc, sh, 64);
    if (lane >= sh) inc += t;
  }
  if (lane == 63) wsum[w] = inc;
  __syncthreads();
  int wof = 0;
  #pragma unroll
  for (int i = 0; i < 4; ++i) if (i < w) wof += wsum[i];
  int run = wof + inc - s;
  offsets[(tid << 2)] = run;     cursor[(tid << 2)] = run;     run += c0;
  offsets[(tid << 2) + 1] = run; cursor[(tid << 2) + 1] = run; run += c1;
  offsets[(tid << 2) + 2] = run; cursor[(tid << 2) + 2] = run; run += c2;
  offsets[(tid << 2) + 3] = run; cursor[(tid << 2) + 3] = run;
}

__global__ void scatter_sorted_kernel(const int* __restrict__ labels, int* __restrict__ cursor,
                                      int* __restrict__ sortedIdx) {
  const int n = blockIdx.x * 256 + threadIdx.x;
  const int pos = atomicAdd(&cursor[labels[n]], 1);
  sortedIdx[pos] = n;
}

// block = (k, slice of 4); thread = channel. Non-atomic f64 partial sums.
template<int TRANS>
__global__ void segsum_kernel(const float* __restrict__ x, const float* __restrict__ xT,
                              const int* __restrict__ sortedIdx, const int* __restrict__ offsets,
                              const int* __restrict__ counts, double* __restrict__ sums4) {
  const int k = blockIdx.x >> 2, sl = blockIdx.x & 3;
  const int tid = threadIdx.x;
  const int cnt = counts[k], off = offsets[k];
  const int i0 = (cnt * sl) >> 2, i1 = (cnt * (sl + 1)) >> 2;
  double acc = 0.0;
  int i = i0;
  for (; i + 4 <= i1; i += 4) {
    float v0, v1, v2, v3;
    if (TRANS) {
      const int na = sortedIdx[off + i],     nb = sortedIdx[off + i + 1];
      const int nc = sortedIdx[off + i + 2], nd = sortedIdx[off + i + 3];
      v0 = xT[((size_t)na << 8) + tid]; v1 = xT[((size_t)nb << 8) + tid];
      v2 = xT[((size_t)nc << 8) + tid]; v3 = xT[((size_t)nd << 8) + tid];
    } else {
      const int na = sortedIdx[off + i],     nb = sortedIdx[off + i + 1];
      const int nc = sortedIdx[off + i + 2], nd = sortedIdx[off + i + 3];
      v0 = x[(size_t)(na >> 10) * (C_ * T_) + (size_t)tid * T_ + (na & 1023)];
      v1 = x[(size_t)(nb >> 10) * (C_ * T_) + (size_t)tid * T_ + (nb & 1023)];
      v2 = x[(size_t)(nc >> 10) * (C_ * T_) + (size_t)tid * T_ + (nc & 1023)];
      v3 = x[(size_t)(nd >> 10) * (C_ * T_) + (size_t)tid * T_ + (nd & 1023)];
    }
    acc += (double)v0; acc += (double)v1; acc += (double)v2; acc += (double)v3;
  }
  for (; i < i1; ++i) {
    const int n = sortedIdx[off + i];
    const float v = TRANS ? xT[((size_t)n << 8) + tid]
                          : x[(size_t)(n >> 10) * (C_ * T_) + (size_t)tid * T_ + (n & 1023)];
    acc += (double)v;
  }
  sums4[((size_t)((sl << 10) + k) << 8) + tid] = acc;
}

// ---------------- launch ----------------
extern "C" void kernel_launch(void* const* d_in, const int* in_sizes, int n_in,
                              void* d_out, int out_size, void* d_ws, size_t ws_size,
                              hipStream_t stream) {
  const float* x = (const float*)d_in[0];
  int* out = (int*)d_out;
  char* ws = (char*)d_ws;

  float*    ema   = (float*)   (ws + 0);             // 1 MiB
  uint16_t* bfH   = (uint16_t*)(ws + 1048576);       // 512 KiB
  uint16_t* bfL   = (uint16_t*)(ws + 1572864);       // 512 KiB
  double*   sums4 = (double*)  (ws + 2097152);       // 8 MiB [4][K][C]
  // sort scratch aliases the sums4 region (pre-loop only)
  unsigned long long* keys = (unsigned long long*)(ws + 2097152);           // 256 KiB
  unsigned long long* barr = (unsigned long long*)(ws + 2097152 + 262144);  // 256 KiB
  int*    val1   = (int*)  (ws + 2097152 + 524288);  // 128 KiB
  const size_t MISC = 2097152 + 8388608;             // 10 MiB
  int*    counts  = (int*)  (ws + MISC);             // 4 KiB
  int*    flagcnt = (int*)  (ws + MISC + 4096);      // 4 KiB (4 B used; adjacent for fused memset)
  int*    offsets = (int*)  (ws + MISC + 8192);      // 4 KiB
  int*    cursor  = (int*)  (ws + MISC + 12288);     // 4 KiB
  double* csq     = (double*)(ws + MISC + 16384);    // 8 KiB
  float*  csq32   = (float*) (ws + MISC + 24576);    // 4 KiB
  int*    perm    = (int*)  (ws + MISC + 28672);     // 4 KiB
  int*    flagidx = (int*)  (ws + MISC + 32768);     // 128 KiB
  int*    sortedIdx = (int*)(ws + MISC + 163840);    // 128 KiB
  int*    bcnt    = (int*)  (ws + MISC + 294912);    // 1 KiB
  int*    boff    = (int*)  (ws + MISC + 295936);    // 2 KiB (257 ints)
  int*    bcur    = (int*)  (ws + MISC + 297984);    // 1 KiB
  const size_t XT_OFF = 11534336;                    // 11 MiB
  float*  xT      = (float*) (ws + XT_OFF);          // 32 MiB
  const bool trans_ok = ws_size >= XT_OFF + (size_t)N_ * C_ * 4;

  uint32_t s1h, s1l, s2h, s2l;
  {
#if JAX_PARTITIONABLE
    uint32_t ch, cl;
    tf2x32(0u, 1u, 0u, 0u, ch, cl);
    tf2x32(0u, 1u, 0u, 1u, s1h, s1l);
    tf2x32(ch, cl, 0u, 1u, s2h, s2l);
#else
    uint32_t a0, a1, b0, b1, ch, cl;
    tf2x32(0u, 1u, 0u, 2u, a0, a1); tf2x32(0u, 1u, 1u, 3u, b0, b1);
    ch = a0; cl = b0; s1h = a1; s1l = b1;
    tf2x32(ch, cl, 0u, 2u, a0, a1); tf2x32(ch, cl, 1u, 3u, b0, b1);
    s2h = a1; s2l = b1;
#endif
  }

  // stable sort round 1 (bucketed rank) -> val1
#if JAX_PARTITIONABLE
  bits_kernel<<<128, 256, 0, stream>>>(s1h, s1l, keys);
#else
  bits_kernel<<<64, 256, 0, stream>>>(s1h, s1l, keys);
#endif
  hipMemsetAsync(bcnt, 0, 1024, stream);
  bhist_kernel<<<128, 256, 0, stream>>>(keys, bcnt);
  bscan_kernel<<<1, 64, 0, stream>>>(bcnt, boff, bcur);
  bscatter_kernel<<<128, 256, 0, stream>>>(keys, bcur, barr);
  brank_kernel<1><<<128, 256, 0, stream>>>(barr, boff, val1, perm);

  // stable sort round 2 -> perm (first K positions)
#if JAX_PARTITIONABLE
  bits_kernel<<<128, 256, 0, stream>>>(s2h, s2l, keys);
#else
  bits_kernel<<<64, 256, 0, stream>>>(s2h, s2l, keys);
#endif
  hipMemsetAsync(bcnt, 0, 1024, stream);
  bhist_kernel<<<128, 256, 0, stream>>>(keys, bcnt);
  bscan_kernel<<<1, 64, 0, stream>>>(bcnt, boff, bcur);
  bscatter_kernel<<<128, 256, 0, stream>>>(keys, bcur, barr);
  brank_kernel<2><<<128, 256, 0, stream>>>(barr, boff, val1, perm);

  init_ema_kernel<<<K_, 256, 0, stream>>>(x, perm, ema, bfH, bfL, csq, csq32);
  if (trans_ok) transpose_kernel<<<1024, 256, 0, stream>>>(x, xT);

  for (int it = 0; it < 10; ++it) {
    hipMemsetAsync(counts, 0, 8192, stream);   // counts + flagcnt (adjacent)
    assign_mfma<<<512, 256, 0, stream>>>(x, (const short8*)bfH, (const short8*)bfL,
                                         csq32, out, flagidx, flagcnt);
    refine_kernel<<<512, 256, 0, stream>>>(x, ema, csq, flagidx, flagcnt, out);
    hist_kernel<<<128, 256, 0, stream>>>(out, counts);
    prefix_kernel<<<1, 256, 0, stream>>>(counts, offsets, cursor);
    scatter_sorted_kernel<<<128, 256, 0, stream>>>(out, cursor, sortedIdx);
    if (trans_ok)
      segsum_kernel<1><<<4096, 256, 0, stream>>>(x, xT, sortedIdx, offsets, counts, sums4);
    else
      segsum_kernel<0><<<4096, 256, 0, stream>>>(x, xT, sortedIdx, offsets, counts, sums4);
    update_kernel<<<K_, 256, 0, stream>>>(ema, bfH, bfL, sums4, counts, csq, csq32);
  }
  hipMemsetAsync(flagcnt, 0, 4, stream);
  assign_mfma<<<512, 256, 0, stream>>>(x, (const short8*)bfH, (const short8*)bfL,
                                       csq32, out, flagidx, flagcnt);
  refine_kernel<<<512, 256, 0, stream>>>(x, ema, csq, flagidx, flagcnt, out);
}

// Round 10
// 2734.046 us; speedup vs baseline: 3.4751x; 1.1241x over previous
//
#include <hip/hip_runtime.h>
#include <stdint.h>

#define JAX_PARTITIONABLE 1

static constexpr int C_ = 256;
static constexpr int T_ = 1024;
static constexpr int N_ = 32768;   // 32 * 1024
static constexpr int K_ = 1024;
static constexpr float MARGIN_ = 0.02f;  // >> 2x the bf16-split dot error bound (~6e-3)

typedef __attribute__((ext_vector_type(8))) short short8;
typedef __attribute__((ext_vector_type(4))) float f32x4;

// ---------------- Threefry2x32, 20 rounds (JAX-compatible) ----------------
__host__ __device__ __forceinline__ void tf2x32(uint32_t k0, uint32_t k1,
                                                uint32_t x0, uint32_t x1,
                                                uint32_t& o0, uint32_t& o1) {
  const uint32_t ks2 = k0 ^ k1 ^ 0x1BD11BDAu;
  uint32_t v0 = x0 + k0, v1 = x1 + k1;
#define TFR(d) { v0 += v1; v1 = (v1 << d) | (v1 >> (32 - d)); v1 ^= v0; }
#define TF4A TFR(13) TFR(15) TFR(26) TFR(6)
#define TF4B TFR(17) TFR(29) TFR(16) TFR(24)
  TF4A v0 += k1;  v1 += ks2 + 1u;
  TF4B v0 += ks2; v1 += k0 + 2u;
  TF4A v0 += k0;  v1 += k1 + 3u;
  TF4B v0 += k1;  v1 += ks2 + 4u;
  TF4A v0 += ks2; v1 += k0 + 5u;
  o0 = v0; o1 = v1;
#undef TFR
#undef TF4A
#undef TF4B
}

// ---------------- bf16 helpers (RN-even) ----------------
__device__ __forceinline__ uint16_t f2bf(float f) {
  const uint32_t u = __float_as_uint(f);
  return (uint16_t)((u + 0x7FFFu + ((u >> 16) & 1u)) >> 16);
}
__device__ __forceinline__ float bf2f(uint16_t h) {
  return __uint_as_float(((uint32_t)h) << 16);
}

// B-fragment writer: layout [ktile(64)][ck(8)][lane(64)][j(8)] bf16 for
// mfma_f32_16x16x32_bf16 B operand: col=lane&15, k=(lane>>4)*8+j, chunk c-base ck*32.
__device__ __forceinline__ void write_bfrag(uint16_t* __restrict__ bH, uint16_t* __restrict__ bL,
                                            int k, int c, float v) {
  const int kt = k >> 4;
  const int lane = (k & 15) + (((c & 31) >> 3) << 4);
  const int ck = c >> 5;
  const int j = c & 7;
  const uint16_t h = f2bf(v);
  const uint16_t l = f2bf(v - bf2f(h));
  const size_t idx = ((((size_t)(kt << 3) + ck) << 6) + lane) * 8 + j;
  bH[idx] = h; bL[idx] = l;
}

// ---------------- PRNG bits (validated R2-R7) ----------------
__global__ void bits_kernel(uint32_t k0, uint32_t k1, unsigned long long* __restrict__ keys) {
#if JAX_PARTITIONABLE
  const int i = blockIdx.x * 256 + threadIdx.x;
  uint32_t o0, o1; tf2x32(k0, k1, 0u, (uint32_t)i, o0, o1);
  keys[i] = (((unsigned long long)(o0 ^ o1)) << 32) | (unsigned)i;
#else
  const int j = blockIdx.x * 256 + threadIdx.x;
  uint32_t o0, o1; tf2x32(k0, k1, (uint32_t)j, (uint32_t)(j + 16384), o0, o1);
  keys[j]         = (((unsigned long long)o0) << 32) | (unsigned)j;
  keys[j + 16384] = (((unsigned long long)o1) << 32) | (unsigned)(j + 16384);
#endif
}

// ---------------- bucketed stable rank (validated R7) ----------------
__global__ void bhist_kernel(const unsigned long long* __restrict__ keys, int* __restrict__ bcnt) {
  const int i = blockIdx.x * 256 + threadIdx.x;
  atomicAdd(&bcnt[(int)(keys[i] >> 56)], 1);
}

__global__ void bscan_kernel(const int* __restrict__ bcnt, int* __restrict__ boff,
                             int* __restrict__ bcur) {
  if (threadIdx.x == 0) {
    int run = 0;
    for (int i = 0; i < 256; ++i) { boff[i] = run; bcur[i] = run; run += bcnt[i]; }
    boff[256] = run;
  }
}

__global__ void bscatter_kernel(const unsigned long long* __restrict__ keys,
                                int* __restrict__ bcur, unsigned long long* __restrict__ barr) {
  const int i = blockIdx.x * 256 + threadIdx.x;
  const unsigned long long k = keys[i];
  const int pos = atomicAdd(&bcur[(int)(k >> 56)], 1);
  barr[pos] = k;
}

template<int ROUND>
__global__ void brank_kernel(const unsigned long long* __restrict__ barr,
                             const int* __restrict__ boff,
                             int* __restrict__ val1, int* __restrict__ perm) {
  const int i = blockIdx.x * 256 + threadIdx.x;
  const unsigned long long my = barr[i];
  const int b = (int)(my >> 56);
  const int lo = boff[b], hi = boff[b + 1];
  int cnt = 0;
  #pragma unroll 4
  for (int j = lo; j < hi; ++j) cnt += (barr[j] < my) ? 1 : 0;
  const int r = lo + cnt;
  const int idx = (int)(uint32_t)my;    // low 32 bits = original position
  if (ROUND == 1) {
    val1[r] = idx;
  } else {
    if (r < K_) perm[r] = val1[idx];
  }
}

// ---------------- one-time transpose x[b][c][t] -> xT[n][c] ----------------
__global__ void transpose_kernel(const float* __restrict__ x, float* __restrict__ xT) {
  __shared__ float tile[256][33];
  const int tid = threadIdx.x;
  const int b = blockIdx.x >> 5, tt = blockIdx.x & 31;
  const int t0 = tt << 5;
  const float* xb = x + (size_t)b * (C_ * T_) + t0;
  #pragma unroll
  for (int i = 0; i < 32; ++i) {
    const int idx = tid + (i << 8);
    const int c = idx >> 5, p = idx & 31;
    tile[c][p] = xb[(size_t)c * T_ + p];
  }
  __syncthreads();
  float* dst = xT + (((size_t)(b << 10) + t0) << 8);
  #pragma unroll
  for (int p = 0; p < 32; ++p)
    dst[((size_t)p << 8) + tid] = tile[tid][p];
}

// ---------------- f64 block reduce ----------------
__device__ __forceinline__ double block_reduce_256_f64(double v, double* red) {
  #pragma unroll
  for (int s = 1; s < 64; s <<= 1) v += __shfl_xor(v, s, 64);
  if ((threadIdx.x & 63) == 0) red[threadIdx.x >> 6] = v;
  __syncthreads();
  return red[0] + red[1] + red[2] + red[3];
}

__global__ void init_ema_kernel(const float* __restrict__ x, const int* __restrict__ perm,
                                float* __restrict__ ema, uint16_t* __restrict__ bfH,
                                uint16_t* __restrict__ bfL,
                                double* __restrict__ csq, float* __restrict__ csq32) {
  __shared__ double red[4];
  const int k = blockIdx.x, c = threadIdx.x;
  const int n = perm[k];
  const int b = n >> 10, t = n & 1023;
  const float v = x[(size_t)b * (C_ * T_) + (size_t)c * T_ + t];
  ema[((size_t)k << 8) + c] = v;
  write_bfrag(bfH, bfL, k, c, v);
  const double s = block_reduce_256_f64((double)v * (double)v, red);
  if (c == 0) { csq[k] = s; csq32[k] = (float)s; }
}

// EMA update in exact f32 reference arithmetic (validated R2-R7); f64 sums from 4 slices.
__global__ void update_kernel(float* __restrict__ ema, uint16_t* __restrict__ bfH,
                              uint16_t* __restrict__ bfL,
                              const double* __restrict__ sums4, const int* __restrict__ counts,
                              double* __restrict__ csq, float* __restrict__ csq32) {
  __shared__ double red[4];
  const int k = blockIdx.x, c = threadIdx.x;
  const size_t idx = ((size_t)k << 8) + c;
  const int cnt = counts[k];
  const float e = ema[idx];
  float center;
  if (cnt == 0) {
    center = e;
  } else {
    double sd = 0.0;
    #pragma unroll
    for (int sl = 0; sl < 4; ++sl) sd += sums4[((size_t)((sl << 10) + k) << 8) + c];
    const float s32 = (float)sd;
    const float denom = __fadd_rn((float)cnt, 1e-5f);
    center = __fdiv_rn(s32, denom);
  }
  const float ne = __fadd_rn(__fmul_rn(e, 0.99f), __fmul_rn(0.01f, center));
  ema[idx] = ne;
  write_bfrag(bfH, bfL, k, c, ne);
  const double s = block_reduce_256_f64((double)ne * (double)ne, red);
  if (c == 0) { csq[k] = s; csq32[k] = (float)s; }
}

// ---------------- MFMA assign: 32 pts/block, depth-2 B prefetch, fused hist ----------
// Block = 32 points (2 Mtiles), 4 waves; wave w owns k-tiles w*16..w*16+15.
// LDS 40 KB -> 3 blocks/CU (12 waves). B loads prefetched 2 iterations ahead.
#define AF2(pl, mt, ck, lane) (((((((pl) << 1) + (mt)) << 3) + (ck)) << 6) + (lane))
#define LOADB(m, dst) { \
  const int _p = (m) >> 3, _c = (m) & 7; \
  const short8* _bp = (_p == 1) ? bfL : bfH; \
  const size_t _a = base0 + ((size_t)_c << 6); \
  dst[0] = _bp[_a]; dst[1] = _bp[_a + 512]; dst[2] = _bp[_a + 1024]; dst[3] = _bp[_a + 1536]; }
#define LOADA(m, A0, A1) { \
  const int _p = (m) >> 3, _c = (m) & 7; \
  const short8* _ap = (_p == 2) ? afL : afH; \
  A0 = _ap[(_c << 6) + lane]; A1 = _ap[512 + (_c << 6) + lane]; }

__global__ __launch_bounds__(256, 3) void assign_mfma(
    const float* __restrict__ x, const short8* __restrict__ bfH, const short8* __restrict__ bfL,
    const float* __restrict__ csq32, int* __restrict__ labels,
    int* __restrict__ flagidx, int* __restrict__ flagcnt, int* __restrict__ counts) {
  __shared__ __align__(16) char smem[40960];
  short8* afrag = (short8*)smem;                        // [2][2][8][64] : 32 KB
  float (*xstage)[32] = (float(*)[32])(smem + 32768);   // [64][32] : 8 KB (prologue only)
  float* mg_d = (float*)(smem + 32768);                 // [4][32] (reused after prologue)
  float* mg_2 = mg_d + 128;
  int*   mg_k = (int*)(mg_2 + 128);

  const int tid = threadIdx.x;
  const int n0 = blockIdx.x << 5;
  const int b = n0 >> 10, t0 = n0 & 1023;
  const float* xb = x + (size_t)b * (C_ * T_) + t0;

  // prologue: 4 quarters of 64 channels; stage f32 then build A-frags (H,L planes)
  #pragma unroll 1
  for (int q = 0; q < 4; ++q) {
    #pragma unroll
    for (int i = 0; i < 8; ++i) {
      const int idx = tid + (i << 8);            // 0..2047
      const int c = idx >> 5, p = idx & 31;
      xstage[c][p] = xb[(size_t)((q << 6) + c) * T_ + p];
    }
    __syncthreads();
    {
      const int lane = tid & 63;
      const int ckh = (tid >> 6) & 1;
      const int mt = tid >> 7;
      const int row = lane & 15;
      const int kof = (lane >> 4) << 3;
      short8 h8, l8;
      #pragma unroll
      for (int j = 0; j < 8; ++j) {
        const float v = xstage[(ckh << 5) + kof + j][(mt << 4) + row];
        const uint16_t hh = f2bf(v);
        h8[j] = (short)hh;
        l8[j] = (short)f2bf(v - bf2f(hh));
      }
      const int ck = (q << 1) + ckh;
      afrag[AF2(0, mt, ck, lane)] = h8;
      afrag[AF2(1, mt, ck, lane)] = l8;
    }
    __syncthreads();
  }

  const int w = tid >> 6, lane = tid & 63;
  const short8* afH = afrag;            // plane 0: [mt][ck][lane], mt stride 512
  const short8* afL = afrag + 1024;     // plane 1

  float bd[8], b2[8]; int bk[8];
  #pragma unroll
  for (int s = 0; s < 8; ++s) { bd[s] = 3.0e38f; b2[s] = 3.0e38f; bk[s] = 0; }

  #pragma unroll 1
  for (int g = 0; g < 4; ++g) {
    const size_t base0 = ((size_t)((w << 4) + (g << 2)) << 9) + lane;  // kt0*512 + lane
    f32x4 acc[2][4];
    #pragma unroll
    for (int mt = 0; mt < 2; ++mt)
      #pragma unroll
      for (int t = 0; t < 4; ++t) acc[mt][t] = (f32x4){0.f, 0.f, 0.f, 0.f};

    short8 bufA[4], bufB[4], a0, a1;
    LOADB(0, bufA);
    LOADB(1, bufB);
    // m = pass*8 + ck; pass 0: H*H, 1: H*L, 2: L*H. 24 iterations, 2 per mm step.
    #pragma unroll 1
    for (int mm = 0; mm < 12; ++mm) {
      const int m0 = mm << 1;
      short8 nb0[4], nb1[4];
      if (mm < 11) LOADB(m0 + 2, nb0);            // issue 2-ahead before MFMAs
      LOADA(m0, a0, a1);
      #pragma unroll
      for (int t = 0; t < 4; ++t) {
        acc[0][t] = __builtin_amdgcn_mfma_f32_16x16x32_bf16(a0, bufA[t], acc[0][t], 0, 0, 0);
        acc[1][t] = __builtin_amdgcn_mfma_f32_16x16x32_bf16(a1, bufA[t], acc[1][t], 0, 0, 0);
      }
      if (mm < 11) { bufA[0] = nb0[0]; bufA[1] = nb0[1]; bufA[2] = nb0[2]; bufA[3] = nb0[3]; }
      if (mm < 11) LOADB(m0 + 3, nb1);
      LOADA(m0 + 1, a0, a1);
      #pragma unroll
      for (int t = 0; t < 4; ++t) {
        acc[0][t] = __builtin_amdgcn_mfma_f32_16x16x32_bf16(a0, bufB[t], acc[0][t], 0, 0, 0);
        acc[1][t] = __builtin_amdgcn_mfma_f32_16x16x32_bf16(a1, bufB[t], acc[1][t], 0, 0, 0);
      }
      if (mm < 11) { bufB[0] = nb1[0]; bufB[1] = nb1[1]; bufB[2] = nb1[2]; bufB[3] = nb1[3]; }
    }

    // epilogue: D layout col=lane&15 (k), row=(lane>>4)*4+r (point); k ascending in g,t
    #pragma unroll
    for (int t = 0; t < 4; ++t) {
      const int kt = (w << 4) + (g << 2) + t;
      const int k = (kt << 4) + (lane & 15);
      const float cq = csq32[k];
      #pragma unroll
      for (int mt = 0; mt < 2; ++mt)
        #pragma unroll
        for (int r = 0; r < 4; ++r) {
          const float d = cq - 2.0f * acc[mt][t][r];
          const int s = (mt << 2) + r;
          if (d < bd[s]) { b2[s] = bd[s]; bd[s] = d; bk[s] = k; }
          else if (d < b2[s]) b2[s] = d;
        }
    }
  }

  // cross-lane argmin over the 16 k-cols (lane bits 0..3); lexicographic (d, k)
  #pragma unroll
  for (int s = 0; s < 8; ++s) {
    #pragma unroll
    for (int sh = 1; sh < 16; sh <<= 1) {
      const float od = __shfl_xor(bd[s], sh, 64);
      const float o2 = __shfl_xor(b2[s], sh, 64);
      const int   ok = __shfl_xor(bk[s], sh, 64);
      if (od < bd[s] || (od == bd[s] && ok < bk[s])) {
        b2[s] = fminf(o2, bd[s]); bd[s] = od; bk[s] = ok;
      } else {
        b2[s] = fminf(b2[s], od);
      }
    }
  }
  if ((lane & 15) == 0) {
    #pragma unroll
    for (int s = 0; s < 8; ++s) {
      const int mt = s >> 2, r = s & 3;
      const int pt = (mt << 4) + ((lane >> 4) << 2) + r;
      mg_d[(w << 5) + pt] = bd[s]; mg_2[(w << 5) + pt] = b2[s]; mg_k[(w << 5) + pt] = bk[s];
    }
  }
  __syncthreads();

  if (tid < 32) {   // merge 4 waves (ascending k-ranges -> ties keep earlier)
    float fb = mg_d[tid], f2 = mg_2[tid]; int fk = mg_k[tid];
    #pragma unroll
    for (int ww = 1; ww < 4; ++ww) {
      const float od = mg_d[(ww << 5) + tid], o2 = mg_2[(ww << 5) + tid];
      const int ok = mg_k[(ww << 5) + tid];
      if (od < fb) { f2 = fminf(fb, o2); fb = od; fk = ok; }
      else f2 = fminf(f2, fminf(od, o2));
    }
    const int n = n0 + tid;
    labels[n] = fk;
    atomicAdd(&counts[fk], 1);                       // fused hist (pre-refine)
    if (f2 - fb <= MARGIN_) { const int p = atomicAdd(flagcnt, 1); flagidx[p] = n; }
  }
}

// ---------------- exact f64 refine of flagged points (patches labels + counts) --------
__global__ void refine_kernel(const float* __restrict__ x, const float* __restrict__ ema,
                              const double* __restrict__ csq,
                              const int* __restrict__ flagidx, const int* __restrict__ flagcnt,
                              int* __restrict__ labels, int* __restrict__ counts) {
  __shared__ float xr[C_];
  __shared__ double rd[4]; __shared__ int rk[4];
  const int tid = threadIdx.x;
  const int cnt = *flagcnt;
  for (int it = blockIdx.x; it < cnt; it += gridDim.x) {
    const int n = flagidx[it];
    const int b = n >> 10, t = n & 1023;
    xr[tid] = x[(size_t)b * (C_ * T_) + (size_t)tid * T_ + t];
    __syncthreads();
    double bdv = 1e300; int bkv = 0;
    #pragma unroll 1
    for (int r = 0; r < 4; ++r) {
      const int k = (r << 8) + tid;
      const float* er = ema + ((size_t)k << 8);
      double acc = 0.0;
      #pragma unroll 4
      for (int c4 = 0; c4 < 64; ++c4) {
        const float4 ev = *(const float4*)(er + (c4 << 2));
        const float4 xv = *(const float4*)(&xr[c4 << 2]);
        acc = fma((double)xv.x, (double)ev.x, acc);
        acc = fma((double)xv.y, (double)ev.y, acc);
        acc = fma((double)xv.z, (double)ev.z, acc);
        acc = fma((double)xv.w, (double)ev.w, acc);
      }
      const double d = csq[k] - 2.0 * acc;
      if (d < bdv) { bdv = d; bkv = k; }
    }
    #pragma unroll
    for (int s = 1; s < 64; s <<= 1) {
      const double od = __shfl_xor(bdv, s, 64);
      const int    ok = __shfl_xor(bkv, s, 64);
      if (od < bdv || (od == bdv && ok < bkv)) { bdv = od; bkv = ok; }
    }
    if ((tid & 63) == 0) { rd[tid >> 6] = bdv; rk[tid >> 6] = bkv; }
    __syncthreads();
    if (tid == 0) {
      #pragma unroll
      for (int wv = 1; wv < 4; ++wv)
        if (rd[wv] < bdv || (rd[wv] == bdv && rk[wv] < bkv)) { bdv = rd[wv]; bkv = rk[wv]; }
      const int old = labels[n];
      if (bkv != old) {
        labels[n] = bkv;
        if (counts != nullptr) { atomicAdd(&counts[old], -1); atomicAdd(&counts[bkv], 1); }
      }
    }
    __syncthreads();
  }
}

// ---------------- deterministic segment sums: prefix -> sort -> gather ----------------
__global__ void prefix_kernel(const int* __restrict__ counts, int* __restrict__ offsets,
                              int* __restrict__ cursor) {
  __shared__ int wsum[4];
  const int tid = threadIdx.x;
  const int lane = tid & 63, w = tid >> 6;
  const int c0 = counts[(tid << 2)], c1 = counts[(tid << 2) + 1];
  const int c2 = counts[(tid << 2) + 2], c3 = counts[(tid << 2) + 3];
  const int s = c0 + c1 + c2 + c3;
  int inc = s;
  #pragma unroll
  for (int sh = 1; sh < 64; sh <<= 1) {
    const int t = __shfl_up(inc, sh, 64);
    if (lane >= sh) inc += t;
  }
  if (lane == 63) wsum[w] = inc;
  __syncthreads();
  int wof = 0;
  #pragma unroll
  for (int i = 0; i < 4; ++i) if (i < w) wof += wsum[i];
  int run = wof + inc - s;
  offsets[(tid << 2)] = run;     cursor[(tid << 2)] = run;     run += c0;
  offsets[(tid << 2) + 1] = run; cursor[(tid << 2) + 1] = run; run += c1;
  offsets[(tid << 2) + 2] = run; cursor[(tid << 2) + 2] = run; run += c2;
  offsets[(tid << 2) + 3] = run; cursor[(tid << 2) + 3] = run;
}

__global__ void scatter_sorted_kernel(const int* __restrict__ labels, int* __restrict__ cursor,
                                      int* __restrict__ sortedIdx) {
  const int n = blockIdx.x * 256 + threadIdx.x;
  const int pos = atomicAdd(&cursor[labels[n]], 1);
  sortedIdx[pos] = n;
}

// block = (k, slice of 4); thread = channel. Non-atomic f64 partial sums.
template<int TRANS>
__global__ void segsum_kernel(const float* __restrict__ x, const float* __restrict__ xT,
                              const int* __restrict__ sortedIdx, const int* __restrict__ offsets,
                              const int* __restrict__ counts, double* __restrict__ sums4) {
  const int k = blockIdx.x >> 2, sl = blockIdx.x & 3;
  const int tid = threadIdx.x;
  const int cnt = counts[k], off = offsets[k];
  const int i0 = (cnt * sl) >> 2, i1 = (cnt * (sl + 1)) >> 2;
  double acc = 0.0;
  int i = i0;
  for (; i + 4 <= i1; i += 4) {
    float v0, v1, v2, v3;
    if (TRANS) {
      const int na = sortedIdx[off + i],     nb = sortedIdx[off + i + 1];
      const int nc = sortedIdx[off + i + 2], nd = sortedIdx[off + i + 3];
      v0 = xT[((size_t)na << 8) + tid]; v1 = xT[((size_t)nb << 8) + tid];
      v2 = xT[((size_t)nc << 8) + tid]; v3 = xT[((size_t)nd << 8) + tid];
    } else {
      const int na = sortedIdx[off + i],     nb = sortedIdx[off + i + 1];
      const int nc = sortedIdx[off + i + 2], nd = sortedIdx[off + i + 3];
      v0 = x[(size_t)(na >> 10) * (C_ * T_) + (size_t)tid * T_ + (na & 1023)];
      v1 = x[(size_t)(nb >> 10) * (C_ * T_) + (size_t)tid * T_ + (nb & 1023)];
      v2 = x[(size_t)(nc >> 10) * (C_ * T_) + (size_t)tid * T_ + (nc & 1023)];
      v3 = x[(size_t)(nd >> 10) * (C_ * T_) + (size_t)tid * T_ + (nd & 1023)];
    }
    acc += (double)v0; acc += (double)v1; acc += (double)v2; acc += (double)v3;
  }
  for (; i < i1; ++i) {
    const int n = sortedIdx[off + i];
    const float v = TRANS ? xT[((size_t)n << 8) + tid]
                          : x[(size_t)(n >> 10) * (C_ * T_) + (size_t)tid * T_ + (n & 1023)];
    acc += (double)v;
  }
  sums4[((size_t)((sl << 10) + k) << 8) + tid] = acc;
}

// ---------------- launch ----------------
extern "C" void kernel_launch(void* const* d_in, const int* in_sizes, int n_in,
                              void* d_out, int out_size, void* d_ws, size_t ws_size,
                              hipStream_t stream) {
  const float* x = (const float*)d_in[0];
  int* out = (int*)d_out;
  char* ws = (char*)d_ws;

  float*    ema   = (float*)   (ws + 0);             // 1 MiB
  uint16_t* bfH   = (uint16_t*)(ws + 1048576);       // 512 KiB
  uint16_t* bfL   = (uint16_t*)(ws + 1572864);       // 512 KiB
  double*   sums4 = (double*)  (ws + 2097152);       // 8 MiB [4][K][C]
  // sort scratch aliases the sums4 region (pre-loop only)
  unsigned long long* keys = (unsigned long long*)(ws + 2097152);           // 256 KiB
  unsigned long long* barr = (unsigned long long*)(ws + 2097152 + 262144);  // 256 KiB
  int*    val1   = (int*)  (ws + 2097152 + 524288);  // 128 KiB
  const size_t MISC = 2097152 + 8388608;             // 10 MiB
  int*    counts  = (int*)  (ws + MISC);             // 4 KiB
  int*    flagcnt = (int*)  (ws + MISC + 4096);      // 4 KiB (4 B used; adjacent for fused memset)
  int*    offsets = (int*)  (ws + MISC + 8192);      // 4 KiB
  int*    cursor  = (int*)  (ws + MISC + 12288);     // 4 KiB
  double* csq     = (double*)(ws + MISC + 16384);    // 8 KiB
  float*  csq32   = (float*) (ws + MISC + 24576);    // 4 KiB
  int*    perm    = (int*)  (ws + MISC + 28672);     // 4 KiB
  int*    flagidx = (int*)  (ws + MISC + 32768);     // 128 KiB
  int*    sortedIdx = (int*)(ws + MISC + 163840);    // 128 KiB
  int*    bcnt    = (int*)  (ws + MISC + 294912);    // 1 KiB
  int*    boff    = (int*)  (ws + MISC + 295936);    // 2 KiB (257 ints)
  int*    bcur    = (int*)  (ws + MISC + 297984);    // 1 KiB
  const size_t XT_OFF = 11534336;                    // 11 MiB
  float*  xT      = (float*) (ws + XT_OFF);          // 32 MiB
  const bool trans_ok = ws_size >= XT_OFF + (size_t)N_ * C_ * 4;

  uint32_t s1h, s1l, s2h, s2l;
  {
#if JAX_PARTITIONABLE
    uint32_t ch, cl;
    tf2x32(0u, 1u, 0u, 0u, ch, cl);
    tf2x32(0u, 1u, 0u, 1u, s1h, s1l);
    tf2x32(ch, cl, 0u, 1u, s2h, s2l);
#else
    uint32_t a0, a1, b0, b1, ch, cl;
    tf2x32(0u, 1u, 0u, 2u, a0, a1); tf2x32(0u, 1u, 1u, 3u, b0, b1);
    ch = a0; cl = b0; s1h = a1; s1l = b1;
    tf2x32(ch, cl, 0u, 2u, a0, a1); tf2x32(ch, cl, 1u, 3u, b0, b1);
    s2h = a1; s2l = b1;
#endif
  }

  // stable sort round 1 (bucketed rank) -> val1
#if JAX_PARTITIONABLE
  bits_kernel<<<128, 256, 0, stream>>>(s1h, s1l, keys);
#else
  bits_kernel<<<64, 256, 0, stream>>>(s1h, s1l, keys);
#endif
  hipMemsetAsync(bcnt, 0, 1024, stream);
  bhist_kernel<<<128, 256, 0, stream>>>(keys, bcnt);
  bscan_kernel<<<1, 64, 0, stream>>>(bcnt, boff, bcur);
  bscatter_kernel<<<128, 256, 0, stream>>>(keys, bcur, barr);
  brank_kernel<1><<<128, 256, 0, stream>>>(barr, boff, val1, perm);

  // stable sort round 2 -> perm (first K positions)
#if JAX_PARTITIONABLE
  bits_kernel<<<128, 256, 0, stream>>>(s2h, s2l, keys);
#else
  bits_kernel<<<64, 256, 0, stream>>>(s2h, s2l, keys);
#endif
  hipMemsetAsync(bcnt, 0, 1024, stream);
  bhist_kernel<<<128, 256, 0, stream>>>(keys, bcnt);
  bscan_kernel<<<1, 64, 0, stream>>>(bcnt, boff, bcur);
  bscatter_kernel<<<128, 256, 0, stream>>>(keys, bcur, barr);
  brank_kernel<2><<<128, 256, 0, stream>>>(barr, boff, val1, perm);

  init_ema_kernel<<<K_, 256, 0, stream>>>(x, perm, ema, bfH, bfL, csq, csq32);
  if (trans_ok) transpose_kernel<<<1024, 256, 0, stream>>>(x, xT);

  for (int it = 0; it < 10; ++it) {
    hipMemsetAsync(counts, 0, 8192, stream);   // counts + flagcnt (adjacent)
    assign_mfma<<<1024, 256, 0, stream>>>(x, (const short8*)bfH, (const short8*)bfL,
                                          csq32, out, flagidx, flagcnt, counts);
    refine_kernel<<<512, 256, 0, stream>>>(x, ema, csq, flagidx, flagcnt, out, counts);
    prefix_kernel<<<1, 256, 0, stream>>>(counts, offsets, cursor);
    scatter_sorted_kernel<<<128, 256, 0, stream>>>(out, cursor, sortedIdx);
    if (trans_ok)
      segsum_kernel<1><<<4096, 256, 0, stream>>>(x, xT, sortedIdx, offsets, counts, sums4);
    else
      segsum_kernel<0><<<4096, 256, 0, stream>>>(x, xT, sortedIdx, offsets, counts, sums4);
    update_kernel<<<K_, 256, 0, stream>>>(ema, bfH, bfL, sums4, counts, csq, csq32);
  }
  hipMemsetAsync(counts, 0, 8192, stream);
  assign_mfma<<<1024, 256, 0, stream>>>(x, (const short8*)bfH, (const short8*)bfL,
                                        csq32, out, flagidx, flagcnt, counts);
  refine_kernel<<<512, 256, 0, stream>>>(x, ema, csq, flagidx, flagcnt, out, nullptr);
}